// Round 1
// baseline (8452.323 us; speedup 1.0000x reference)
//
#include <hip/hip_runtime.h>
#include <hip/hip_bf16.h>
#include <math.h>

// Model dims
#define BB     16
#define LL     197
#define DD     384
#define DEPTH  24
#define DI     768
#define DSN    16
#define DTR    24
#define NC     1000
#define TT     (BB*LL)      // 3152 tokens
#define NPATCH 196
#define EPSV   1e-5f

// ---------------------------------------------------------------------------
// init: zero residual stream, write cls token row (hid[b,0,:] = cls + pos[0])
// ---------------------------------------------------------------------------
__global__ __launch_bounds__(256) void k_init(const float* __restrict__ cls,
                                              const float* __restrict__ pos,
                                              float* __restrict__ res,
                                              float* __restrict__ hid) {
  int i = blockIdx.x * 256 + threadIdx.x;
  if (i < TT * DD) res[i] = 0.f;
  if (i < BB * DD) {
    int b = i / DD, d = i % DD;
    hid[(size_t)(b * LL) * DD + d] = cls[d] + pos[d];
  }
}

// ---------------------------------------------------------------------------
// patch embed as GEMM with fused im2col: hid[b,1+p,d] = patch + pb + pos
// M = 3136 patches, N = 384, K = 768 (3*16*16)
// ---------------------------------------------------------------------------
__global__ __launch_bounds__(256) void k_patch(const float* __restrict__ x,
                                               const float* __restrict__ pw,
                                               const float* __restrict__ pb,
                                               const float* __restrict__ pos,
                                               float* __restrict__ hid) {
  __shared__ float As[16][68];
  __shared__ float Bs[16][68];
  const int tid = threadIdx.x;
  const int m0 = blockIdx.x * 64;  // 49 tiles * 64 = 3136 exact
  const int n0 = blockIdx.y * 64;  // 6 tiles * 64 = 384 exact
  const int lr = tid >> 2;         // 0..63
  const int lk = (tid & 3) << 2;   // 0,4,8,12
  const int tm = (tid >> 4) << 2;
  const int tn = (tid & 15) << 2;
  float acc[4][4] = {};
  const int m = m0 + lr;
  const int b = m / NPATCH;
  const int p = m % NPATCH;
  const int ph = p / 14, pwi = p % 14;
  for (int k0 = 0; k0 < 768; k0 += 16) {
    int k = k0 + lk;
    int c = k >> 8, rr = (k >> 4) & 15, kw = k & 15;
    float4 av = *(const float4*)&x[(size_t)(((b * 3 + c) * 224) + (ph * 16 + rr)) * 224 +
                                   (pwi * 16 + kw)];
    As[lk + 0][lr] = av.x; As[lk + 1][lr] = av.y;
    As[lk + 2][lr] = av.z; As[lk + 3][lr] = av.w;
    float4 bv = *(const float4*)&pw[(size_t)(n0 + lr) * 768 + k];
    Bs[lk + 0][lr] = bv.x; Bs[lk + 1][lr] = bv.y;
    Bs[lk + 2][lr] = bv.z; Bs[lk + 3][lr] = bv.w;
    __syncthreads();
#pragma unroll
    for (int kk = 0; kk < 16; kk++) {
      float4 a4 = *(const float4*)&As[kk][tm];
      float4 b4 = *(const float4*)&Bs[kk][tn];
      float a[4] = {a4.x, a4.y, a4.z, a4.w};
      float bb_[4] = {b4.x, b4.y, b4.z, b4.w};
#pragma unroll
      for (int i = 0; i < 4; i++)
#pragma unroll
        for (int j = 0; j < 4; j++) acc[i][j] += a[i] * bb_[j];
    }
    __syncthreads();
  }
#pragma unroll
  for (int i = 0; i < 4; i++) {
    int mm = m0 + tm + i;
    int b2 = mm / NPATCH, pp = mm % NPATCH;
    int tok = b2 * LL + 1 + pp;
#pragma unroll
    for (int j = 0; j < 4; j++) {
      int d = n0 + tn + j;
      hid[(size_t)tok * DD + d] = acc[i][j] + pb[d] + pos[(size_t)(1 + pp) * DD + d];
    }
  }
}

// ---------------------------------------------------------------------------
// generic tiled fp32 GEMM: C[M,N] = A[M,K] (row, lda) * Bw[N,K]^T (row, ldb)
// EPI: 0 = plain store, 1 = softplus(acc + bias[n])
// ---------------------------------------------------------------------------
template <int EPI, bool FASTA, bool FASTB>
__global__ __launch_bounds__(256) void k_gemm64(const float* __restrict__ A, int lda,
                                                const float* __restrict__ Bw, int ldb,
                                                float* __restrict__ C, int ldc,
                                                int M, int N, int K,
                                                const float* __restrict__ bias) {
  __shared__ float As[16][68];
  __shared__ float Bs[16][68];
  const int tid = threadIdx.x;
  const int m0 = blockIdx.x * 64;
  const int n0 = blockIdx.y * 64;
  const int lr = tid >> 2;
  const int lk = (tid & 3) << 2;
  const int tm = (tid >> 4) << 2;
  const int tn = (tid & 15) << 2;
  float acc[4][4] = {};
  const int m = m0 + lr;
  const int n = n0 + lr;
  for (int k0 = 0; k0 < K; k0 += 16) {
    float a0 = 0, a1 = 0, a2 = 0, a3 = 0;
    if (m < M) {
      if (FASTA) {
        float4 v = *(const float4*)&A[(size_t)m * lda + k0 + lk];
        a0 = v.x; a1 = v.y; a2 = v.z; a3 = v.w;
      } else {
        int k = k0 + lk;
        if (k + 0 < K) a0 = A[(size_t)m * lda + k + 0];
        if (k + 1 < K) a1 = A[(size_t)m * lda + k + 1];
        if (k + 2 < K) a2 = A[(size_t)m * lda + k + 2];
        if (k + 3 < K) a3 = A[(size_t)m * lda + k + 3];
      }
    }
    As[lk + 0][lr] = a0; As[lk + 1][lr] = a1;
    As[lk + 2][lr] = a2; As[lk + 3][lr] = a3;
    float b0 = 0, b1 = 0, b2 = 0, b3 = 0;
    if (n < N) {
      if (FASTB) {
        float4 v = *(const float4*)&Bw[(size_t)n * ldb + k0 + lk];
        b0 = v.x; b1 = v.y; b2 = v.z; b3 = v.w;
      } else {
        int k = k0 + lk;
        if (k + 0 < K) b0 = Bw[(size_t)n * ldb + k + 0];
        if (k + 1 < K) b1 = Bw[(size_t)n * ldb + k + 1];
        if (k + 2 < K) b2 = Bw[(size_t)n * ldb + k + 2];
        if (k + 3 < K) b3 = Bw[(size_t)n * ldb + k + 3];
      }
    }
    Bs[lk + 0][lr] = b0; Bs[lk + 1][lr] = b1;
    Bs[lk + 2][lr] = b2; Bs[lk + 3][lr] = b3;
    __syncthreads();
#pragma unroll
    for (int kk = 0; kk < 16; kk++) {
      float4 a4 = *(const float4*)&As[kk][tm];
      float4 b4 = *(const float4*)&Bs[kk][tn];
      float a[4] = {a4.x, a4.y, a4.z, a4.w};
      float bb_[4] = {b4.x, b4.y, b4.z, b4.w};
#pragma unroll
      for (int i = 0; i < 4; i++)
#pragma unroll
        for (int j = 0; j < 4; j++) acc[i][j] += a[i] * bb_[j];
    }
    __syncthreads();
  }
#pragma unroll
  for (int i = 0; i < 4; i++) {
    int mm = m0 + tm + i;
    if (mm >= M) continue;
#pragma unroll
    for (int j = 0; j < 4; j++) {
      int nn = n0 + tn + j;
      if (nn >= N) continue;
      float v = acc[i][j];
      if (EPI == 1) {
        v += bias[nn];
        v = (v > 20.f) ? v : log1pf(__expf(v));
      }
      C[(size_t)mm * ldc + nn] = v;
    }
  }
}

// ---------------------------------------------------------------------------
// skinny GEMM (BM=16, BN=64) for x_proj (N=56): more blocks in flight
// ---------------------------------------------------------------------------
template <bool FASTB>
__global__ __launch_bounds__(256) void k_gemm16(const float* __restrict__ A, int lda,
                                                const float* __restrict__ Bw, int ldb,
                                                float* __restrict__ C, int ldc,
                                                int M, int N, int K) {
  __shared__ float As[16][17];
  __shared__ float Bs[16][68];
  const int tid = threadIdx.x;
  const int m0 = blockIdx.x * 16;
  const int n0 = blockIdx.y * 64;
  const int am = tid >> 4, ak = tid & 15;
  const int bn = tid >> 2, bk = (tid & 3) << 2;
  const int tm = tid >> 4;
  const int tn = (tid & 15) << 2;
  float acc[4] = {0, 0, 0, 0};
  for (int k0 = 0; k0 < K; k0 += 16) {
    {
      float v = 0;
      int mm = m0 + am, k = k0 + ak;
      if (mm < M && k < K) v = A[(size_t)mm * lda + k];
      As[ak][am] = v;
    }
    {
      float b0 = 0, b1 = 0, b2 = 0, b3 = 0;
      int nn = n0 + bn;
      if (nn < N) {
        if (FASTB) {
          float4 v = *(const float4*)&Bw[(size_t)nn * ldb + k0 + bk];
          b0 = v.x; b1 = v.y; b2 = v.z; b3 = v.w;
        } else {
          int k = k0 + bk;
          if (k + 0 < K) b0 = Bw[(size_t)nn * ldb + k + 0];
          if (k + 1 < K) b1 = Bw[(size_t)nn * ldb + k + 1];
          if (k + 2 < K) b2 = Bw[(size_t)nn * ldb + k + 2];
          if (k + 3 < K) b3 = Bw[(size_t)nn * ldb + k + 3];
        }
      }
      Bs[bk + 0][bn] = b0; Bs[bk + 1][bn] = b1;
      Bs[bk + 2][bn] = b2; Bs[bk + 3][bn] = b3;
    }
    __syncthreads();
#pragma unroll
    for (int kk = 0; kk < 16; kk++) {
      float a = As[kk][tm];
      float4 b4 = *(const float4*)&Bs[kk][tn];
      acc[0] += a * b4.x; acc[1] += a * b4.y;
      acc[2] += a * b4.z; acc[3] += a * b4.w;
    }
    __syncthreads();
  }
  int mm = m0 + tm;
  if (mm < M) {
#pragma unroll
    for (int j = 0; j < 4; j++) {
      int nn = n0 + tn + j;
      if (nn < N) C[(size_t)mm * ldc + nn] = acc[j];
    }
  }
}

// ---------------------------------------------------------------------------
// res += hid; u = LN(res) * nw + nb   (one block per token, 128 thr, 3 elem/thr)
// ---------------------------------------------------------------------------
__global__ __launch_bounds__(128) void k_addln(float* __restrict__ res,
                                               const float* __restrict__ hid,
                                               float* __restrict__ u,
                                               const float* __restrict__ nw,
                                               const float* __restrict__ nb) {
  const int t = blockIdx.x;
  const int tid = threadIdx.x;
  float r[3];
  float s = 0.f, sq = 0.f;
#pragma unroll
  for (int j = 0; j < 3; j++) {
    int d = tid + j * 128;
    float v = res[(size_t)t * DD + d] + hid[(size_t)t * DD + d];
    res[(size_t)t * DD + d] = v;
    r[j] = v;
    s += v; sq += v * v;
  }
#pragma unroll
  for (int o = 32; o > 0; o >>= 1) { s += __shfl_xor(s, o); sq += __shfl_xor(sq, o); }
  __shared__ float ls[2], lq[2];
  int w = tid >> 6;
  if ((tid & 63) == 0) { ls[w] = s; lq[w] = sq; }
  __syncthreads();
  float st = ls[0] + ls[1], qt = lq[0] + lq[1];
  float mu = st * (1.f / 384.f);
  float var = qt * (1.f / 384.f) - mu * mu;
  float rs = rsqrtf(var + EPSV);
#pragma unroll
  for (int j = 0; j < 3; j++) {
    int d = tid + j * 128;
    u[(size_t)t * DD + d] = (r[j] - mu) * rs * nw[d] + nb[d];
  }
}

// ---------------------------------------------------------------------------
// causal depthwise conv (k=4, left pad 3) + bias + SiLU
// xz[:, 0:768] is xc_pre; writes xc
// ---------------------------------------------------------------------------
__global__ __launch_bounds__(256) void k_conv(const float* __restrict__ xz,
                                              const float* __restrict__ wc,
                                              const float* __restrict__ bc,
                                              float* __restrict__ xc) {
  int i = blockIdx.x * 256 + threadIdx.x;  // over TT*DI
  if (i >= TT * DI) return;
  int e = i % DI;
  int t = i / DI;
  int b = t / LL, l = t % LL;
  float4 w = *(const float4*)&wc[e * 4];
  float acc = bc[e];
  const float* base = xz + (size_t)(b * LL) * (2 * DI) + e;
  if (l >= 3) acc += base[(size_t)(l - 3) * (2 * DI)] * w.x;
  if (l >= 2) acc += base[(size_t)(l - 2) * (2 * DI)] * w.y;
  if (l >= 1) acc += base[(size_t)(l - 1) * (2 * DI)] * w.z;
  acc += base[(size_t)l * (2 * DI)] * w.w;
  xc[i] = acc * (1.f / (1.f + __expf(-acc)));
}

// ---------------------------------------------------------------------------
// selective scan: thread = (b, e, n); h in register; shfl-reduce over n (16)
// y[t,e] = (sum_n h*C + xc*Dp) * silu(z)
// ---------------------------------------------------------------------------
__global__ __launch_bounds__(256) void k_scan(const float* __restrict__ dt,
                                              const float* __restrict__ xc,
                                              const float* __restrict__ xz,
                                              const float* __restrict__ dbl,
                                              const float* __restrict__ Alog,
                                              const float* __restrict__ Dp,
                                              float* __restrict__ y) {
  const int tid = threadIdx.x;
  const int n = tid & 15;
  const int es = tid >> 4;  // 0..15
  const int b = blockIdx.x / (DI / 16);
  const int eg = blockIdx.x % (DI / 16);
  const int e = eg * 16 + es;
  const float A = -__expf(Alog[(size_t)e * DSN + n]);
  const float dp = Dp[e];
  float h = 0.f;
  const size_t tbase = (size_t)b * LL;
  for (int l = 0; l < LL; l++) {
    size_t t = tbase + l;
    float dtv = dt[t * DI + e];
    float xcv = xc[t * DI + e];
    float zv = xz[t * (2 * DI) + DI + e];
    float Bv = dbl[t * 56 + DTR + n];
    float Cv = dbl[t * 56 + DTR + DSN + n];
    float dA = __expf(dtv * A);
    h = dA * h + dtv * xcv * Bv;
    float contrib = h * Cv;
#pragma unroll
    for (int o = 1; o < 16; o <<= 1) contrib += __shfl_xor(contrib, o);
    if (n == 0) {
      float yv = contrib + xcv * dp;
      float sz = zv * (1.f / (1.f + __expf(-zv)));
      y[t * DI + e] = yv * sz;
    }
  }
}

// ---------------------------------------------------------------------------
// final: LN(res[b,0]+hid[b,0]) -> head GEMM (one block per batch)
// ---------------------------------------------------------------------------
__global__ __launch_bounds__(256) void k_final(const float* __restrict__ res,
                                               const float* __restrict__ hid,
                                               const float* __restrict__ nfw,
                                               const float* __restrict__ nfb,
                                               const float* __restrict__ hw,
                                               const float* __restrict__ hb,
                                               float* __restrict__ out) {
  const int b = blockIdx.x;
  const int tid = threadIdx.x;
  __shared__ float u0[DD];
  __shared__ float ls[4], lq[4];
  const size_t t0 = (size_t)b * LL * DD;
  float v0, v1 = 0.f;
  float s = 0.f, sq = 0.f;
  v0 = res[t0 + tid] + hid[t0 + tid];
  s += v0; sq += v0 * v0;
  if (tid < 128) {
    v1 = res[t0 + 256 + tid] + hid[t0 + 256 + tid];
    s += v1; sq += v1 * v1;
  }
#pragma unroll
  for (int o = 32; o > 0; o >>= 1) { s += __shfl_xor(s, o); sq += __shfl_xor(sq, o); }
  if ((tid & 63) == 0) { ls[tid >> 6] = s; lq[tid >> 6] = sq; }
  __syncthreads();
  float st = ls[0] + ls[1] + ls[2] + ls[3];
  float qt = lq[0] + lq[1] + lq[2] + lq[3];
  float mu = st * (1.f / 384.f);
  float var = qt * (1.f / 384.f) - mu * mu;
  float rs = rsqrtf(var + EPSV);
  u0[tid] = (v0 - mu) * rs * nfw[tid] + nfb[tid];
  if (tid < 128) u0[256 + tid] = (v1 - mu) * rs * nfw[256 + tid] + nfb[256 + tid];
  __syncthreads();
  for (int c = tid; c < NC; c += 256) {
    float acc = hb[c];
    const float* wrow = hw + (size_t)c * DD;
    for (int d = 0; d < DD; d += 4) {
      float4 w4 = *(const float4*)&wrow[d];
      acc += u0[d] * w4.x + u0[d + 1] * w4.y + u0[d + 2] * w4.z + u0[d + 3] * w4.w;
    }
    out[(size_t)b * NC + c] = acc;
  }
}

// ---------------------------------------------------------------------------
extern "C" void kernel_launch(void* const* d_in, const int* in_sizes, int n_in,
                              void* d_out, int out_size, void* d_ws, size_t ws_size,
                              hipStream_t stream) {
  const float* x       = (const float*)d_in[0];
  const float* patch_w = (const float*)d_in[1];
  const float* patch_b = (const float*)d_in[2];
  const float* cls     = (const float*)d_in[3];
  const float* pos     = (const float*)d_in[4];
  const float* in_proj = (const float*)d_in[5];
  const float* conv_w  = (const float*)d_in[6];
  const float* conv_b  = (const float*)d_in[7];
  const float* x_proj  = (const float*)d_in[8];
  const float* dt_w    = (const float*)d_in[9];
  const float* dt_b    = (const float*)d_in[10];
  const float* A_log   = (const float*)d_in[11];
  const float* D_ssm   = (const float*)d_in[12];
  const float* out_w   = (const float*)d_in[13];
  const float* norm_w  = (const float*)d_in[14];
  const float* norm_b  = (const float*)d_in[15];
  const float* normf_w = (const float*)d_in[16];
  const float* normf_b = (const float*)d_in[17];
  const float* head_w  = (const float*)d_in[18];
  const float* head_b  = (const float*)d_in[19];
  float* out = (float*)d_out;

  float* ws = (float*)d_ws;
  float* res = ws;  ws += (size_t)TT * DD;
  float* hid = ws;  ws += (size_t)TT * DD;
  float* u   = ws;  ws += (size_t)TT * DD;
  float* xzb = ws;  ws += (size_t)TT * 2 * DI;
  float* xcb = ws;  ws += (size_t)TT * DI;
  float* dbl = ws;  ws += (size_t)TT * 56;
  float* dtb = ws;  ws += (size_t)TT * DI;
  float* yb  = ws;  ws += (size_t)TT * DI;

  k_init<<<(TT * DD + 255) / 256, 256, 0, stream>>>(cls, pos, res, hid);
  k_patch<<<dim3(49, 6), 256, 0, stream>>>(x, patch_w, patch_b, pos, hid);

  for (int layer = 0; layer < DEPTH; layer++) {
    k_addln<<<TT, 128, 0, stream>>>(res, hid, u, norm_w + layer * DD, norm_b + layer * DD);
    // in_proj: u (3152,384) @ Win^T (1536,384) -> xz (3152,1536)
    k_gemm64<0, true, true><<<dim3(50, 24), 256, 0, stream>>>(
        u, DD, in_proj + (size_t)layer * 2 * DI * DD, DD, xzb, 2 * DI, TT, 2 * DI, DD, nullptr);
    k_conv<<<(TT * DI) / 256, 256, 0, stream>>>(xzb, conv_w + layer * DI * 4,
                                                conv_b + layer * DI, xcb);
    // x_proj: xc (3152,768) @ Wx^T (56,768) -> dbl (3152,56)
    k_gemm16<true><<<dim3(197, 1), 256, 0, stream>>>(
        xcb, DI, x_proj + (size_t)layer * 56 * DI, DI, dbl, 56, TT, 56, DI);
    // dt: dbl[:, :24] (lda=56) @ Wdt^T (768,24) + bdt, softplus -> dt (3152,768)
    k_gemm64<1, false, false><<<dim3(50, 12), 256, 0, stream>>>(
        dbl, 56, dt_w + (size_t)layer * DI * DTR, DTR, dtb, DI, TT, DI, DTR,
        dt_b + layer * DI);
    k_scan<<<BB * (DI / 16), 256, 0, stream>>>(dtb, xcb, xzb, dbl,
                                               A_log + (size_t)layer * DI * DSN,
                                               D_ssm + layer * DI, yb);
    // out_proj: y (3152,768) @ Wout^T (384,768) -> hid (3152,384)
    k_gemm64<0, true, true><<<dim3(50, 6), 256, 0, stream>>>(
        yb, DI, out_w + (size_t)layer * DD * DI, DI, hid, DD, TT, DD, DI, nullptr);
  }

  k_final<<<BB, 256, 0, stream>>>(res, hid, normf_w, normf_b, head_w, head_b, out);
}

// Round 2
// 7549.236 us; speedup vs baseline: 1.1196x; 1.1196x over previous
//
#include <hip/hip_runtime.h>
#include <hip/hip_bf16.h>
#include <math.h>

// Model dims
#define BB     16
#define LL     197
#define DD     384
#define DEPTH  24
#define DI     768
#define DSN    16
#define DTR    24
#define NC     1000
#define TT     (BB*LL)      // 3152 tokens
#define NPATCH 196
#define EPSV   1e-5f

// chunked scan config
#define NCHUNK 6
#define LCH    33           // ceil(197/6)

// ---------------------------------------------------------------------------
// init: zero residual stream, write cls token row (hid[b,0,:] = cls + pos[0])
// ---------------------------------------------------------------------------
__global__ __launch_bounds__(256) void k_init(const float* __restrict__ cls,
                                              const float* __restrict__ pos,
                                              float* __restrict__ res,
                                              float* __restrict__ hid) {
  int i = blockIdx.x * 256 + threadIdx.x;
  if (i < TT * DD) res[i] = 0.f;
  if (i < BB * DD) {
    int b = i / DD, d = i % DD;
    hid[(size_t)(b * LL) * DD + d] = cls[d] + pos[d];
  }
}

// ---------------------------------------------------------------------------
// patch embed as GEMM with fused im2col: hid[b,1+p,d] = patch + pb + pos
// ---------------------------------------------------------------------------
__global__ __launch_bounds__(256) void k_patch(const float* __restrict__ x,
                                               const float* __restrict__ pw,
                                               const float* __restrict__ pb,
                                               const float* __restrict__ pos,
                                               float* __restrict__ hid) {
  __shared__ float As[16][68];
  __shared__ float Bs[16][68];
  const int tid = threadIdx.x;
  const int m0 = blockIdx.x * 64;
  const int n0 = blockIdx.y * 64;
  const int lr = tid >> 2;
  const int lk = (tid & 3) << 2;
  const int tm = (tid >> 4) << 2;
  const int tn = (tid & 15) << 2;
  float acc[4][4] = {};
  const int m = m0 + lr;
  const int b = m / NPATCH;
  const int p = m % NPATCH;
  const int ph = p / 14, pwi = p % 14;
  for (int k0 = 0; k0 < 768; k0 += 16) {
    int k = k0 + lk;
    int c = k >> 8, rr = (k >> 4) & 15, kw = k & 15;
    float4 av = *(const float4*)&x[(size_t)(((b * 3 + c) * 224) + (ph * 16 + rr)) * 224 +
                                   (pwi * 16 + kw)];
    As[lk + 0][lr] = av.x; As[lk + 1][lr] = av.y;
    As[lk + 2][lr] = av.z; As[lk + 3][lr] = av.w;
    float4 bv = *(const float4*)&pw[(size_t)(n0 + lr) * 768 + k];
    Bs[lk + 0][lr] = bv.x; Bs[lk + 1][lr] = bv.y;
    Bs[lk + 2][lr] = bv.z; Bs[lk + 3][lr] = bv.w;
    __syncthreads();
#pragma unroll
    for (int kk = 0; kk < 16; kk++) {
      float4 a4 = *(const float4*)&As[kk][tm];
      float4 b4 = *(const float4*)&Bs[kk][tn];
      float a[4] = {a4.x, a4.y, a4.z, a4.w};
      float bb_[4] = {b4.x, b4.y, b4.z, b4.w};
#pragma unroll
      for (int i = 0; i < 4; i++)
#pragma unroll
        for (int j = 0; j < 4; j++) acc[i][j] += a[i] * bb_[j];
    }
    __syncthreads();
  }
#pragma unroll
  for (int i = 0; i < 4; i++) {
    int mm = m0 + tm + i;
    int b2 = mm / NPATCH, pp = mm % NPATCH;
    int tok = b2 * LL + 1 + pp;
#pragma unroll
    for (int j = 0; j < 4; j++) {
      int d = n0 + tn + j;
      hid[(size_t)tok * DD + d] = acc[i][j] + pb[d] + pos[(size_t)(1 + pp) * DD + d];
    }
  }
}

// ---------------------------------------------------------------------------
// generic tiled fp32 GEMM: C[M,N] = A[M,K] (row, lda) * Bw[N,K]^T (row, ldb)
// EPI: 0 = plain store, 1 = softplus(acc + bias[n])
// ---------------------------------------------------------------------------
template <int EPI, bool FASTA, bool FASTB>
__global__ __launch_bounds__(256) void k_gemm64(const float* __restrict__ A, int lda,
                                                const float* __restrict__ Bw, int ldb,
                                                float* __restrict__ C, int ldc,
                                                int M, int N, int K,
                                                const float* __restrict__ bias) {
  __shared__ float As[16][68];
  __shared__ float Bs[16][68];
  const int tid = threadIdx.x;
  const int m0 = blockIdx.x * 64;
  const int n0 = blockIdx.y * 64;
  const int lr = tid >> 2;
  const int lk = (tid & 3) << 2;
  const int tm = (tid >> 4) << 2;
  const int tn = (tid & 15) << 2;
  float acc[4][4] = {};
  const int m = m0 + lr;
  const int n = n0 + lr;
  for (int k0 = 0; k0 < K; k0 += 16) {
    float a0 = 0, a1 = 0, a2 = 0, a3 = 0;
    if (m < M) {
      if (FASTA) {
        float4 v = *(const float4*)&A[(size_t)m * lda + k0 + lk];
        a0 = v.x; a1 = v.y; a2 = v.z; a3 = v.w;
      } else {
        int k = k0 + lk;
        if (k + 0 < K) a0 = A[(size_t)m * lda + k + 0];
        if (k + 1 < K) a1 = A[(size_t)m * lda + k + 1];
        if (k + 2 < K) a2 = A[(size_t)m * lda + k + 2];
        if (k + 3 < K) a3 = A[(size_t)m * lda + k + 3];
      }
    }
    As[lk + 0][lr] = a0; As[lk + 1][lr] = a1;
    As[lk + 2][lr] = a2; As[lk + 3][lr] = a3;
    float b0 = 0, b1 = 0, b2 = 0, b3 = 0;
    if (n < N) {
      if (FASTB) {
        float4 v = *(const float4*)&Bw[(size_t)n * ldb + k0 + lk];
        b0 = v.x; b1 = v.y; b2 = v.z; b3 = v.w;
      } else {
        int k = k0 + lk;
        if (k + 0 < K) b0 = Bw[(size_t)n * ldb + k + 0];
        if (k + 1 < K) b1 = Bw[(size_t)n * ldb + k + 1];
        if (k + 2 < K) b2 = Bw[(size_t)n * ldb + k + 2];
        if (k + 3 < K) b3 = Bw[(size_t)n * ldb + k + 3];
      }
    }
    Bs[lk + 0][lr] = b0; Bs[lk + 1][lr] = b1;
    Bs[lk + 2][lr] = b2; Bs[lk + 3][lr] = b3;
    __syncthreads();
#pragma unroll
    for (int kk = 0; kk < 16; kk++) {
      float4 a4 = *(const float4*)&As[kk][tm];
      float4 b4 = *(const float4*)&Bs[kk][tn];
      float a[4] = {a4.x, a4.y, a4.z, a4.w};
      float bb_[4] = {b4.x, b4.y, b4.z, b4.w};
#pragma unroll
      for (int i = 0; i < 4; i++)
#pragma unroll
        for (int j = 0; j < 4; j++) acc[i][j] += a[i] * bb_[j];
    }
    __syncthreads();
  }
#pragma unroll
  for (int i = 0; i < 4; i++) {
    int mm = m0 + tm + i;
    if (mm >= M) continue;
#pragma unroll
    for (int j = 0; j < 4; j++) {
      int nn = n0 + tn + j;
      if (nn >= N) continue;
      float v = acc[i][j];
      if (EPI == 1) {
        v += bias[nn];
        v = (v > 20.f) ? v : log1pf(__expf(v));
      }
      C[(size_t)mm * ldc + nn] = v;
    }
  }
}

// ---------------------------------------------------------------------------
// skinny GEMM (BM=16, BN=64) for x_proj (N=56)
// ---------------------------------------------------------------------------
template <bool FASTB>
__global__ __launch_bounds__(256) void k_gemm16(const float* __restrict__ A, int lda,
                                                const float* __restrict__ Bw, int ldb,
                                                float* __restrict__ C, int ldc,
                                                int M, int N, int K) {
  __shared__ float As[16][17];
  __shared__ float Bs[16][68];
  const int tid = threadIdx.x;
  const int m0 = blockIdx.x * 16;
  const int n0 = blockIdx.y * 64;
  const int am = tid >> 4, ak = tid & 15;
  const int bn = tid >> 2, bk = (tid & 3) << 2;
  const int tm = tid >> 4;
  const int tn = (tid & 15) << 2;
  float acc[4] = {0, 0, 0, 0};
  for (int k0 = 0; k0 < K; k0 += 16) {
    {
      float v = 0;
      int mm = m0 + am, k = k0 + ak;
      if (mm < M && k < K) v = A[(size_t)mm * lda + k];
      As[ak][am] = v;
    }
    {
      float b0 = 0, b1 = 0, b2 = 0, b3 = 0;
      int nn = n0 + bn;
      if (nn < N) {
        if (FASTB) {
          float4 v = *(const float4*)&Bw[(size_t)nn * ldb + k0 + bk];
          b0 = v.x; b1 = v.y; b2 = v.z; b3 = v.w;
        } else {
          int k = k0 + bk;
          if (k + 0 < K) b0 = Bw[(size_t)nn * ldb + k + 0];
          if (k + 1 < K) b1 = Bw[(size_t)nn * ldb + k + 1];
          if (k + 2 < K) b2 = Bw[(size_t)nn * ldb + k + 2];
          if (k + 3 < K) b3 = Bw[(size_t)nn * ldb + k + 3];
        }
      }
      Bs[bk + 0][bn] = b0; Bs[bk + 1][bn] = b1;
      Bs[bk + 2][bn] = b2; Bs[bk + 3][bn] = b3;
    }
    __syncthreads();
#pragma unroll
    for (int kk = 0; kk < 16; kk++) {
      float a = As[kk][tm];
      float4 b4 = *(const float4*)&Bs[kk][tn];
      acc[0] += a * b4.x; acc[1] += a * b4.y;
      acc[2] += a * b4.z; acc[3] += a * b4.w;
    }
    __syncthreads();
  }
  int mm = m0 + tm;
  if (mm < M) {
#pragma unroll
    for (int j = 0; j < 4; j++) {
      int nn = n0 + tn + j;
      if (nn < N) C[(size_t)mm * ldc + nn] = acc[j];
    }
  }
}

// ---------------------------------------------------------------------------
// res += hid; u = LN(res) * nw + nb
// ---------------------------------------------------------------------------
__global__ __launch_bounds__(128) void k_addln(float* __restrict__ res,
                                               const float* __restrict__ hid,
                                               float* __restrict__ u,
                                               const float* __restrict__ nw,
                                               const float* __restrict__ nb) {
  const int t = blockIdx.x;
  const int tid = threadIdx.x;
  float r[3];
  float s = 0.f, sq = 0.f;
#pragma unroll
  for (int j = 0; j < 3; j++) {
    int d = tid + j * 128;
    float v = res[(size_t)t * DD + d] + hid[(size_t)t * DD + d];
    res[(size_t)t * DD + d] = v;
    r[j] = v;
    s += v; sq += v * v;
  }
#pragma unroll
  for (int o = 32; o > 0; o >>= 1) { s += __shfl_xor(s, o); sq += __shfl_xor(sq, o); }
  __shared__ float ls[2], lq[2];
  int w = tid >> 6;
  if ((tid & 63) == 0) { ls[w] = s; lq[w] = sq; }
  __syncthreads();
  float st = ls[0] + ls[1], qt = lq[0] + lq[1];
  float mu = st * (1.f / 384.f);
  float var = qt * (1.f / 384.f) - mu * mu;
  float rs = rsqrtf(var + EPSV);
#pragma unroll
  for (int j = 0; j < 3; j++) {
    int d = tid + j * 128;
    u[(size_t)t * DD + d] = (r[j] - mu) * rs * nw[d] + nb[d];
  }
}

// ---------------------------------------------------------------------------
// causal depthwise conv (k=4, left pad 3) + bias + SiLU
// ---------------------------------------------------------------------------
__global__ __launch_bounds__(256) void k_conv(const float* __restrict__ xz,
                                              const float* __restrict__ wc,
                                              const float* __restrict__ bc,
                                              float* __restrict__ xc) {
  int i = blockIdx.x * 256 + threadIdx.x;
  if (i >= TT * DI) return;
  int e = i % DI;
  int t = i / DI;
  int b = t / LL, l = t % LL;
  float4 w = *(const float4*)&wc[e * 4];
  float acc = bc[e];
  const float* base = xz + (size_t)(b * LL) * (2 * DI) + e;
  if (l >= 3) acc += base[(size_t)(l - 3) * (2 * DI)] * w.x;
  if (l >= 2) acc += base[(size_t)(l - 2) * (2 * DI)] * w.y;
  if (l >= 1) acc += base[(size_t)(l - 1) * (2 * DI)] * w.z;
  acc += base[(size_t)l * (2 * DI)] * w.w;
  xc[i] = acc * (1.f / (1.f + __expf(-acc)));
}

// ---------------------------------------------------------------------------
// chunked selective scan, pass 1: per (b,e,n,chunk) local scan from h=0.
// Emits Aprod (prod of dA) and Hend (local scan end) per chunk.
// ---------------------------------------------------------------------------
__global__ __launch_bounds__(256) void k_scan1(const float* __restrict__ dt,
                                               const float* __restrict__ xc,
                                               const float* __restrict__ dbl,
                                               const float* __restrict__ Alog,
                                               float* __restrict__ Aprod,
                                               float* __restrict__ Hend) {
  const int tid = threadIdx.x;
  const int n = tid & 15;
  const int es = tid >> 4;
  const int b = blockIdx.x / (DI / 16);
  const int eg = blockIdx.x % (DI / 16);
  const int c = blockIdx.y;
  const int e = eg * 16 + es;
  const float A = -__expf(Alog[(size_t)e * DSN + n]);
  float h = 0.f, ap = 1.f;
  const int l0 = c * LCH;
  const int l1 = (l0 + LCH < LL) ? (l0 + LCH) : LL;
  const size_t tbase = (size_t)b * LL;
  for (int l = l0; l < l1; l++) {
    size_t t = tbase + l;
    float dtv = dt[t * DI + e];
    float xcv = xc[t * DI + e];
    float Bv = dbl[t * 56 + DTR + n];
    float dA = __expf(dtv * A);
    h = dA * h + dtv * xcv * Bv;
    ap *= dA;
  }
  size_t ci = (((size_t)c * BB + b) * DI + e) * DSN + n;
  Aprod[ci] = ap;
  Hend[ci] = h;
}

// ---------------------------------------------------------------------------
// carry combine: per (b,e,n), sequentially fold chunk carries; rewrite
// Hc[c] in-place with the INCOMING state h_in for chunk c.
// ---------------------------------------------------------------------------
__global__ __launch_bounds__(256) void k_scan_carry(const float* __restrict__ Aprod,
                                                    float* __restrict__ Hc) {
  int i = blockIdx.x * 256 + threadIdx.x;  // over BB*DI*DSN
  if (i >= BB * DI * DSN) return;
  const size_t stride = (size_t)BB * DI * DSN;
  float hin = 0.f;
#pragma unroll
  for (int c = 0; c < NCHUNK; c++) {
    size_t ci = (size_t)c * stride + i;
    float a = Aprod[ci];
    float he = Hc[ci];
    Hc[ci] = hin;
    hin = a * hin + he;
  }
}

// ---------------------------------------------------------------------------
// pass 2: re-run local scan from h_in, reduce over n (shfl width 16),
// gate with silu(z), add D skip. y MAY alias dt (read-before-write within
// the same wave for each (t,e); chunks partition t across blocks).
// ---------------------------------------------------------------------------
__global__ __launch_bounds__(256) void k_scan2(const float* __restrict__ dt,
                                               const float* __restrict__ xc,
                                               const float* __restrict__ xz,
                                               const float* __restrict__ dbl,
                                               const float* __restrict__ Alog,
                                               const float* __restrict__ Dp,
                                               const float* __restrict__ Hin,
                                               float* __restrict__ y) {
  const int tid = threadIdx.x;
  const int n = tid & 15;
  const int es = tid >> 4;
  const int b = blockIdx.x / (DI / 16);
  const int eg = blockIdx.x % (DI / 16);
  const int c = blockIdx.y;
  const int e = eg * 16 + es;
  const float A = -__expf(Alog[(size_t)e * DSN + n]);
  const float dp = Dp[e];
  size_t ci = (((size_t)c * BB + b) * DI + e) * DSN + n;
  float h = Hin[ci];
  const int l0 = c * LCH;
  const int l1 = (l0 + LCH < LL) ? (l0 + LCH) : LL;
  const size_t tbase = (size_t)b * LL;
  for (int l = l0; l < l1; l++) {
    size_t t = tbase + l;
    float dtv = dt[t * DI + e];
    float xcv = xc[t * DI + e];
    float zv = xz[t * (2 * DI) + DI + e];
    float Bv = dbl[t * 56 + DTR + n];
    float Cv = dbl[t * 56 + DTR + DSN + n];
    float dA = __expf(dtv * A);
    h = dA * h + dtv * xcv * Bv;
    float contrib = h * Cv;
#pragma unroll
    for (int o = 1; o < 16; o <<= 1) contrib += __shfl_xor(contrib, o);
    if (n == 0) {
      float yv = contrib + xcv * dp;
      float sz = zv * (1.f / (1.f + __expf(-zv)));
      y[t * DI + e] = yv * sz;
    }
  }
}

// ---------------------------------------------------------------------------
// final: LN(res[b,0]+hid[b,0]) -> head GEMM (one block per batch)
// ---------------------------------------------------------------------------
__global__ __launch_bounds__(256) void k_final(const float* __restrict__ res,
                                               const float* __restrict__ hid,
                                               const float* __restrict__ nfw,
                                               const float* __restrict__ nfb,
                                               const float* __restrict__ hw,
                                               const float* __restrict__ hb,
                                               float* __restrict__ out) {
  const int b = blockIdx.x;
  const int tid = threadIdx.x;
  __shared__ float u0[DD];
  __shared__ float ls[4], lq[4];
  const size_t t0 = (size_t)b * LL * DD;
  float v0, v1 = 0.f;
  float s = 0.f, sq = 0.f;
  v0 = res[t0 + tid] + hid[t0 + tid];
  s += v0; sq += v0 * v0;
  if (tid < 128) {
    v1 = res[t0 + 256 + tid] + hid[t0 + 256 + tid];
    s += v1; sq += v1 * v1;
  }
#pragma unroll
  for (int o = 32; o > 0; o >>= 1) { s += __shfl_xor(s, o); sq += __shfl_xor(sq, o); }
  if ((tid & 63) == 0) { ls[tid >> 6] = s; lq[tid >> 6] = sq; }
  __syncthreads();
  float st = ls[0] + ls[1] + ls[2] + ls[3];
  float qt = lq[0] + lq[1] + lq[2] + lq[3];
  float mu = st * (1.f / 384.f);
  float var = qt * (1.f / 384.f) - mu * mu;
  float rs = rsqrtf(var + EPSV);
  u0[tid] = (v0 - mu) * rs * nfw[tid] + nfb[tid];
  if (tid < 128) u0[256 + tid] = (v1 - mu) * rs * nfw[256 + tid] + nfb[256 + tid];
  __syncthreads();
  for (int c = tid; c < NC; c += 256) {
    float acc = hb[c];
    const float* wrow = hw + (size_t)c * DD;
    for (int d = 0; d < DD; d += 4) {
      float4 w4 = *(const float4*)&wrow[d];
      acc += u0[d] * w4.x + u0[d + 1] * w4.y + u0[d + 2] * w4.z + u0[d + 3] * w4.w;
    }
    out[(size_t)b * NC + c] = acc;
  }
}

// ---------------------------------------------------------------------------
extern "C" void kernel_launch(void* const* d_in, const int* in_sizes, int n_in,
                              void* d_out, int out_size, void* d_ws, size_t ws_size,
                              hipStream_t stream) {
  const float* x       = (const float*)d_in[0];
  const float* patch_w = (const float*)d_in[1];
  const float* patch_b = (const float*)d_in[2];
  const float* cls     = (const float*)d_in[3];
  const float* pos     = (const float*)d_in[4];
  const float* in_proj = (const float*)d_in[5];
  const float* conv_w  = (const float*)d_in[6];
  const float* conv_b  = (const float*)d_in[7];
  const float* x_proj  = (const float*)d_in[8];
  const float* dt_w    = (const float*)d_in[9];
  const float* dt_b    = (const float*)d_in[10];
  const float* A_log   = (const float*)d_in[11];
  const float* D_ssm   = (const float*)d_in[12];
  const float* out_w   = (const float*)d_in[13];
  const float* norm_w  = (const float*)d_in[14];
  const float* norm_b  = (const float*)d_in[15];
  const float* normf_w = (const float*)d_in[16];
  const float* normf_b = (const float*)d_in[17];
  const float* head_w  = (const float*)d_in[18];
  const float* head_b  = (const float*)d_in[19];
  float* out = (float*)d_out;

  float* ws = (float*)d_ws;
  float* res = ws;  ws += (size_t)TT * DD;
  float* hid = ws;  ws += (size_t)TT * DD;
  float* u   = ws;  ws += (size_t)TT * DD;
  float* xzb = ws;  ws += (size_t)TT * 2 * DI;
  float* xcb = ws;  ws += (size_t)TT * DI;
  float* dbl = ws;  ws += (size_t)TT * 56;
  float* dtb = ws;  ws += (size_t)TT * DI;
  float* crg = ws;  ws += (size_t)TT * DI;   // carry region (2*NCHUNK*BB*DI*DSN <= TT*DI)
  float* yb  = dtb;                          // y aliases dt (safe: same-wave RAW order)
  float* Aprod = crg;
  float* Hc    = crg + (size_t)NCHUNK * BB * DI * DSN;

  k_init<<<(TT * DD + 255) / 256, 256, 0, stream>>>(cls, pos, res, hid);
  k_patch<<<dim3(49, 6), 256, 0, stream>>>(x, patch_w, patch_b, pos, hid);

  for (int layer = 0; layer < DEPTH; layer++) {
    k_addln<<<TT, 128, 0, stream>>>(res, hid, u, norm_w + layer * DD, norm_b + layer * DD);
    // in_proj: u (3152,384) @ Win^T (1536,384) -> xz (3152,1536)
    k_gemm64<0, true, true><<<dim3(50, 24), 256, 0, stream>>>(
        u, DD, in_proj + (size_t)layer * 2 * DI * DD, DD, xzb, 2 * DI, TT, 2 * DI, DD, nullptr);
    k_conv<<<(TT * DI) / 256, 256, 0, stream>>>(xzb, conv_w + layer * DI * 4,
                                                conv_b + layer * DI, xcb);
    // x_proj: xc (3152,768) @ Wx^T (56,768) -> dbl (3152,56)
    k_gemm16<true><<<dim3(197, 1), 256, 0, stream>>>(
        xcb, DI, x_proj + (size_t)layer * 56 * DI, DI, dbl, 56, TT, 56, DI);
    // dt: dbl[:, :24] (lda=56) @ Wdt^T (768,24) + bdt, softplus -> dt (3152,768)
    k_gemm64<1, false, false><<<dim3(50, 12), 256, 0, stream>>>(
        dbl, 56, dt_w + (size_t)layer * DI * DTR, DTR, dtb, DI, TT, DI, DTR,
        dt_b + layer * DI);
    // chunked scan: pass1 -> carry -> pass2
    k_scan1<<<dim3(BB * (DI / 16), NCHUNK), 256, 0, stream>>>(
        dtb, xcb, dbl, A_log + (size_t)layer * DI * DSN, Aprod, Hc);
    k_scan_carry<<<(BB * DI * DSN + 255) / 256, 256, 0, stream>>>(Aprod, Hc);
    k_scan2<<<dim3(BB * (DI / 16), NCHUNK), 256, 0, stream>>>(
        dtb, xcb, xzb, dbl, A_log + (size_t)layer * DI * DSN,
        D_ssm + layer * DI, Hc, yb);
    // out_proj: y (3152,768) @ Wout^T (384,768) -> hid (3152,384)
    k_gemm64<0, true, true><<<dim3(50, 6), 256, 0, stream>>>(
        yb, DI, out_w + (size_t)layer * DD * DI, DI, hid, DD, TT, DD, DI, nullptr);
  }

  k_final<<<BB, 256, 0, stream>>>(res, hid, normf_w, normf_b, head_w, head_b, out);
}

// Round 3
// 4629.638 us; speedup vs baseline: 1.8257x; 1.6306x over previous
//
#include <hip/hip_runtime.h>
#include <hip/hip_bf16.h>
#include <math.h>

// Model dims
#define BB     16
#define LL     197
#define DD     384
#define DEPTH  24
#define DI     768
#define DSN    16
#define DTR    24
#define NC     1000
#define TT     (BB*LL)      // 3152 tokens
#define NPATCH 196
#define EPSV   1e-5f

// chunked scan config
#define NCHUNK 6
#define LCH    33           // ceil(197/6)
#define STILE  16           // tokens staged per LDS tile

typedef __attribute__((ext_vector_type(8))) short short8;
typedef __attribute__((ext_vector_type(4))) float f32x4;

__device__ __forceinline__ short f2bf(float f) {
  union { float f; unsigned u; } v; v.f = f;
  unsigned u = v.u + 0x7fffu + ((v.u >> 16) & 1u);
  return (short)(u >> 16);
}

// ---------------------------------------------------------------------------
// init
// ---------------------------------------------------------------------------
__global__ __launch_bounds__(256) void k_init(const float* __restrict__ cls,
                                              const float* __restrict__ pos,
                                              float* __restrict__ res,
                                              float* __restrict__ hid) {
  int i = blockIdx.x * 256 + threadIdx.x;
  if (i < TT * DD) res[i] = 0.f;
  if (i < BB * DD) {
    int b = i / DD, d = i % DD;
    hid[(size_t)(b * LL) * DD + d] = cls[d] + pos[d];
  }
}

// ---------------------------------------------------------------------------
// patch embed GEMM with fused im2col (fp32; runs once)
// ---------------------------------------------------------------------------
__global__ __launch_bounds__(256) void k_patch(const float* __restrict__ x,
                                               const float* __restrict__ pw,
                                               const float* __restrict__ pb,
                                               const float* __restrict__ pos,
                                               float* __restrict__ hid) {
  __shared__ float As[16][68];
  __shared__ float Bs[16][68];
  const int tid = threadIdx.x;
  const int m0 = blockIdx.x * 64;
  const int n0 = blockIdx.y * 64;
  const int lr = tid >> 2;
  const int lk = (tid & 3) << 2;
  const int tm = (tid >> 4) << 2;
  const int tn = (tid & 15) << 2;
  float acc[4][4] = {};
  const int m = m0 + lr;
  const int b = m / NPATCH;
  const int p = m % NPATCH;
  const int ph = p / 14, pwi = p % 14;
  for (int k0 = 0; k0 < 768; k0 += 16) {
    int k = k0 + lk;
    int c = k >> 8, rr = (k >> 4) & 15, kw = k & 15;
    float4 av = *(const float4*)&x[(size_t)(((b * 3 + c) * 224) + (ph * 16 + rr)) * 224 +
                                   (pwi * 16 + kw)];
    As[lk + 0][lr] = av.x; As[lk + 1][lr] = av.y;
    As[lk + 2][lr] = av.z; As[lk + 3][lr] = av.w;
    float4 bv = *(const float4*)&pw[(size_t)(n0 + lr) * 768 + k];
    Bs[lk + 0][lr] = bv.x; Bs[lk + 1][lr] = bv.y;
    Bs[lk + 2][lr] = bv.z; Bs[lk + 3][lr] = bv.w;
    __syncthreads();
#pragma unroll
    for (int kk = 0; kk < 16; kk++) {
      float4 a4 = *(const float4*)&As[kk][tm];
      float4 b4 = *(const float4*)&Bs[kk][tn];
      float a[4] = {a4.x, a4.y, a4.z, a4.w};
      float bb_[4] = {b4.x, b4.y, b4.z, b4.w};
#pragma unroll
      for (int i = 0; i < 4; i++)
#pragma unroll
        for (int j = 0; j < 4; j++) acc[i][j] += a[i] * bb_[j];
    }
    __syncthreads();
  }
#pragma unroll
  for (int i = 0; i < 4; i++) {
    int mm = m0 + tm + i;
    int b2 = mm / NPATCH, pp = mm % NPATCH;
    int tok = b2 * LL + 1 + pp;
#pragma unroll
    for (int j = 0; j < 4; j++) {
      int d = n0 + tn + j;
      hid[(size_t)tok * DD + d] = acc[i][j] + pb[d] + pos[(size_t)(1 + pp) * DD + d];
    }
  }
}

// ---------------------------------------------------------------------------
// bf16 MFMA GEMM: C[M,N] = A[M,K] * W[N,K]^T, fp32 in/out, bf16 compute.
// 64x64 tile, 4 waves each 32x32 (2x2 of 16x16x32 MFMA). K%32==0, N%64==0.
// Frag layout (m89/m92-verified): A/B lane holds 8 contiguous k at
// k=(lane>>4)*8, row=lane&15; C/D col=lane&15, row=(lane>>4)*4+reg.
// ---------------------------------------------------------------------------
__global__ __launch_bounds__(256) void k_gemm_mfma(const float* __restrict__ A, int lda,
                                                   const float* __restrict__ W, int ldb,
                                                   float* __restrict__ C, int ldc,
                                                   int M, int N, int K) {
  __shared__ short sA[64 * 40];  // 40-short row stride (80B, 16B-aligned, conflict-safe)
  __shared__ short sB[64 * 40];
  const int tid = threadIdx.x;
  const int m0 = blockIdx.x * 64, n0 = blockIdx.y * 64;
  const int srow = tid >> 2;        // 0..63
  const int skq = (tid & 3) * 8;    // 0,8,16,24
  const int lane = tid & 63, w = tid >> 6;
  const int wm = (w >> 1) * 32, wn = (w & 1) * 32;
  const int fr = lane & 15;
  const int fk = (lane >> 4) * 8;
  f32x4 acc[2][2] = {};
  const int am = m0 + srow;
  const bool aok = am < M;
  const float* Arow = A + (size_t)am * lda + skq;
  const float* Wrow = W + (size_t)(n0 + srow) * ldb + skq;
  for (int k0 = 0; k0 < K; k0 += 32) {
    float4 a0 = {0, 0, 0, 0}, a1 = {0, 0, 0, 0};
    if (aok) {
      a0 = *(const float4*)&Arow[k0];
      a1 = *(const float4*)&Arow[k0 + 4];
    }
    float4 b0 = *(const float4*)&Wrow[k0];
    float4 b1 = *(const float4*)&Wrow[k0 + 4];
    short8 av = {f2bf(a0.x), f2bf(a0.y), f2bf(a0.z), f2bf(a0.w),
                 f2bf(a1.x), f2bf(a1.y), f2bf(a1.z), f2bf(a1.w)};
    short8 bv = {f2bf(b0.x), f2bf(b0.y), f2bf(b0.z), f2bf(b0.w),
                 f2bf(b1.x), f2bf(b1.y), f2bf(b1.z), f2bf(b1.w)};
    *(short8*)&sA[srow * 40 + skq] = av;
    *(short8*)&sB[srow * 40 + skq] = bv;
    __syncthreads();
    short8 af0 = *(const short8*)&sA[(wm + fr) * 40 + fk];
    short8 af1 = *(const short8*)&sA[(wm + 16 + fr) * 40 + fk];
    short8 bf0 = *(const short8*)&sB[(wn + fr) * 40 + fk];
    short8 bf1 = *(const short8*)&sB[(wn + 16 + fr) * 40 + fk];
    acc[0][0] = __builtin_amdgcn_mfma_f32_16x16x32_bf16(af0, bf0, acc[0][0], 0, 0, 0);
    acc[0][1] = __builtin_amdgcn_mfma_f32_16x16x32_bf16(af0, bf1, acc[0][1], 0, 0, 0);
    acc[1][0] = __builtin_amdgcn_mfma_f32_16x16x32_bf16(af1, bf0, acc[1][0], 0, 0, 0);
    acc[1][1] = __builtin_amdgcn_mfma_f32_16x16x32_bf16(af1, bf1, acc[1][1], 0, 0, 0);
    __syncthreads();
  }
#pragma unroll
  for (int i = 0; i < 2; i++)
#pragma unroll
    for (int j = 0; j < 2; j++)
#pragma unroll
      for (int p = 0; p < 4; p++) {
        int mm = m0 + wm + i * 16 + (lane >> 4) * 4 + p;
        int nn = n0 + wn + j * 16 + (lane & 15);
        if (mm < M) C[(size_t)mm * ldc + nn] = acc[i][j][p];
      }
}

// ---------------------------------------------------------------------------
// generic tiled fp32 GEMM (still used for dt projection)
// ---------------------------------------------------------------------------
template <int EPI, bool FASTA, bool FASTB>
__global__ __launch_bounds__(256) void k_gemm64(const float* __restrict__ A, int lda,
                                                const float* __restrict__ Bw, int ldb,
                                                float* __restrict__ C, int ldc,
                                                int M, int N, int K,
                                                const float* __restrict__ bias) {
  __shared__ float As[16][68];
  __shared__ float Bs[16][68];
  const int tid = threadIdx.x;
  const int m0 = blockIdx.x * 64;
  const int n0 = blockIdx.y * 64;
  const int lr = tid >> 2;
  const int lk = (tid & 3) << 2;
  const int tm = (tid >> 4) << 2;
  const int tn = (tid & 15) << 2;
  float acc[4][4] = {};
  const int m = m0 + lr;
  const int n = n0 + lr;
  for (int k0 = 0; k0 < K; k0 += 16) {
    float a0 = 0, a1 = 0, a2 = 0, a3 = 0;
    if (m < M) {
      if (FASTA) {
        float4 v = *(const float4*)&A[(size_t)m * lda + k0 + lk];
        a0 = v.x; a1 = v.y; a2 = v.z; a3 = v.w;
      } else {
        int k = k0 + lk;
        if (k + 0 < K) a0 = A[(size_t)m * lda + k + 0];
        if (k + 1 < K) a1 = A[(size_t)m * lda + k + 1];
        if (k + 2 < K) a2 = A[(size_t)m * lda + k + 2];
        if (k + 3 < K) a3 = A[(size_t)m * lda + k + 3];
      }
    }
    As[lk + 0][lr] = a0; As[lk + 1][lr] = a1;
    As[lk + 2][lr] = a2; As[lk + 3][lr] = a3;
    float b0 = 0, b1 = 0, b2 = 0, b3 = 0;
    if (n < N) {
      if (FASTB) {
        float4 v = *(const float4*)&Bw[(size_t)n * ldb + k0 + lk];
        b0 = v.x; b1 = v.y; b2 = v.z; b3 = v.w;
      } else {
        int k = k0 + lk;
        if (k + 0 < K) b0 = Bw[(size_t)n * ldb + k + 0];
        if (k + 1 < K) b1 = Bw[(size_t)n * ldb + k + 1];
        if (k + 2 < K) b2 = Bw[(size_t)n * ldb + k + 2];
        if (k + 3 < K) b3 = Bw[(size_t)n * ldb + k + 3];
      }
    }
    Bs[lk + 0][lr] = b0; Bs[lk + 1][lr] = b1;
    Bs[lk + 2][lr] = b2; Bs[lk + 3][lr] = b3;
    __syncthreads();
#pragma unroll
    for (int kk = 0; kk < 16; kk++) {
      float4 a4 = *(const float4*)&As[kk][tm];
      float4 b4 = *(const float4*)&Bs[kk][tn];
      float a[4] = {a4.x, a4.y, a4.z, a4.w};
      float bb_[4] = {b4.x, b4.y, b4.z, b4.w};
#pragma unroll
      for (int i = 0; i < 4; i++)
#pragma unroll
        for (int j = 0; j < 4; j++) acc[i][j] += a[i] * bb_[j];
    }
    __syncthreads();
  }
#pragma unroll
  for (int i = 0; i < 4; i++) {
    int mm = m0 + tm + i;
    if (mm >= M) continue;
#pragma unroll
    for (int j = 0; j < 4; j++) {
      int nn = n0 + tn + j;
      if (nn >= N) continue;
      float v = acc[i][j];
      if (EPI == 1) {
        v += bias[nn];
        v = (v > 20.f) ? v : log1pf(__expf(v));
      }
      C[(size_t)mm * ldc + nn] = v;
    }
  }
}

// ---------------------------------------------------------------------------
// skinny GEMM (BM=16, BN=64) for x_proj (N=56)
// ---------------------------------------------------------------------------
template <bool FASTB>
__global__ __launch_bounds__(256) void k_gemm16(const float* __restrict__ A, int lda,
                                                const float* __restrict__ Bw, int ldb,
                                                float* __restrict__ C, int ldc,
                                                int M, int N, int K) {
  __shared__ float As[16][17];
  __shared__ float Bs[16][68];
  const int tid = threadIdx.x;
  const int m0 = blockIdx.x * 16;
  const int n0 = blockIdx.y * 64;
  const int am = tid >> 4, ak = tid & 15;
  const int bn = tid >> 2, bk = (tid & 3) << 2;
  const int tm = tid >> 4;
  const int tn = (tid & 15) << 2;
  float acc[4] = {0, 0, 0, 0};
  for (int k0 = 0; k0 < K; k0 += 16) {
    {
      float v = 0;
      int mm = m0 + am, k = k0 + ak;
      if (mm < M && k < K) v = A[(size_t)mm * lda + k];
      As[ak][am] = v;
    }
    {
      float b0 = 0, b1 = 0, b2 = 0, b3 = 0;
      int nn = n0 + bn;
      if (nn < N) {
        if (FASTB) {
          float4 v = *(const float4*)&Bw[(size_t)nn * ldb + k0 + bk];
          b0 = v.x; b1 = v.y; b2 = v.z; b3 = v.w;
        } else {
          int k = k0 + bk;
          if (k + 0 < K) b0 = Bw[(size_t)nn * ldb + k + 0];
          if (k + 1 < K) b1 = Bw[(size_t)nn * ldb + k + 1];
          if (k + 2 < K) b2 = Bw[(size_t)nn * ldb + k + 2];
          if (k + 3 < K) b3 = Bw[(size_t)nn * ldb + k + 3];
        }
      }
      Bs[bk + 0][bn] = b0; Bs[bk + 1][bn] = b1;
      Bs[bk + 2][bn] = b2; Bs[bk + 3][bn] = b3;
    }
    __syncthreads();
#pragma unroll
    for (int kk = 0; kk < 16; kk++) {
      float a = As[kk][tm];
      float4 b4 = *(const float4*)&Bs[kk][tn];
      acc[0] += a * b4.x; acc[1] += a * b4.y;
      acc[2] += a * b4.z; acc[3] += a * b4.w;
    }
    __syncthreads();
  }
  int mm = m0 + tm;
  if (mm < M) {
#pragma unroll
    for (int j = 0; j < 4; j++) {
      int nn = n0 + tn + j;
      if (nn < N) C[(size_t)mm * ldc + nn] = acc[j];
    }
  }
}

// ---------------------------------------------------------------------------
// res += hid; u = LN(res) * nw + nb
// ---------------------------------------------------------------------------
__global__ __launch_bounds__(128) void k_addln(float* __restrict__ res,
                                               const float* __restrict__ hid,
                                               float* __restrict__ u,
                                               const float* __restrict__ nw,
                                               const float* __restrict__ nb) {
  const int t = blockIdx.x;
  const int tid = threadIdx.x;
  float r[3];
  float s = 0.f, sq = 0.f;
#pragma unroll
  for (int j = 0; j < 3; j++) {
    int d = tid + j * 128;
    float v = res[(size_t)t * DD + d] + hid[(size_t)t * DD + d];
    res[(size_t)t * DD + d] = v;
    r[j] = v;
    s += v; sq += v * v;
  }
#pragma unroll
  for (int o = 32; o > 0; o >>= 1) { s += __shfl_xor(s, o); sq += __shfl_xor(sq, o); }
  __shared__ float ls[2], lq[2];
  int w = tid >> 6;
  if ((tid & 63) == 0) { ls[w] = s; lq[w] = sq; }
  __syncthreads();
  float st = ls[0] + ls[1], qt = lq[0] + lq[1];
  float mu = st * (1.f / 384.f);
  float var = qt * (1.f / 384.f) - mu * mu;
  float rs = rsqrtf(var + EPSV);
#pragma unroll
  for (int j = 0; j < 3; j++) {
    int d = tid + j * 128;
    u[(size_t)t * DD + d] = (r[j] - mu) * rs * nw[d] + nb[d];
  }
}

// ---------------------------------------------------------------------------
// causal depthwise conv (k=4, left pad 3) + bias + SiLU
// ---------------------------------------------------------------------------
__global__ __launch_bounds__(256) void k_conv(const float* __restrict__ xz,
                                              const float* __restrict__ wc,
                                              const float* __restrict__ bc,
                                              float* __restrict__ xc) {
  int i = blockIdx.x * 256 + threadIdx.x;
  if (i >= TT * DI) return;
  int e = i % DI;
  int t = i / DI;
  int b = t / LL, l = t % LL;
  float4 w = *(const float4*)&wc[e * 4];
  float acc = bc[e];
  const float* base = xz + (size_t)(b * LL) * (2 * DI) + e;
  if (l >= 3) acc += base[(size_t)(l - 3) * (2 * DI)] * w.x;
  if (l >= 2) acc += base[(size_t)(l - 2) * (2 * DI)] * w.y;
  if (l >= 1) acc += base[(size_t)(l - 1) * (2 * DI)] * w.z;
  acc += base[(size_t)l * (2 * DI)] * w.w;
  xc[i] = acc * (1.f / (1.f + __expf(-acc)));
}

// ---------------------------------------------------------------------------
// chunked scan pass 1 with LDS token staging (16-token tiles, coalesced)
// ---------------------------------------------------------------------------
__global__ __launch_bounds__(256) void k_scan1(const float* __restrict__ dt,
                                               const float* __restrict__ xc,
                                               const float* __restrict__ dbl,
                                               const float* __restrict__ Alog,
                                               float* __restrict__ Aprod,
                                               float* __restrict__ Hend) {
  __shared__ float sDt[STILE][16], sXc[STILE][16], sB[STILE][16];
  const int tid = threadIdx.x;
  const int n = tid & 15;
  const int es = tid >> 4;
  const int b = blockIdx.x / (DI / 16);
  const int eg = blockIdx.x % (DI / 16);
  const int c = blockIdx.y;
  const int e0 = eg * 16;
  const int e = e0 + es;
  const int tok = tid >> 4, idx = tid & 15;
  const float A = -__expf(Alog[(size_t)e * DSN + n]);
  float h = 0.f, ap = 1.f;
  const int l0 = c * LCH;
  const int l1 = (l0 + LCH < LL) ? (l0 + LCH) : LL;
  const size_t tbase = (size_t)b * LL;
  for (int lt = l0; lt < l1; lt += STILE) {
    int cnt = (l1 - lt < STILE) ? (l1 - lt) : STILE;
    if (tok < cnt) {
      size_t t = tbase + lt + tok;
      sDt[tok][idx] = dt[t * DI + e0 + idx];
      sXc[tok][idx] = xc[t * DI + e0 + idx];
      sB[tok][idx] = dbl[t * 56 + DTR + idx];
    }
    __syncthreads();
    for (int j = 0; j < cnt; j++) {
      float dtv = sDt[j][es];
      float dA = __expf(dtv * A);
      h = dA * h + (dtv * sXc[j][es]) * sB[j][n];
      ap *= dA;
    }
    __syncthreads();
  }
  size_t ci = (((size_t)c * BB + b) * DI + e) * DSN + n;
  Aprod[ci] = ap;
  Hend[ci] = h;
}

// ---------------------------------------------------------------------------
// carry combine
// ---------------------------------------------------------------------------
__global__ __launch_bounds__(256) void k_scan_carry(const float* __restrict__ Aprod,
                                                    float* __restrict__ Hc) {
  int i = blockIdx.x * 256 + threadIdx.x;
  if (i >= BB * DI * DSN) return;
  const size_t stride = (size_t)BB * DI * DSN;
  float hin = 0.f;
#pragma unroll
  for (int c = 0; c < NCHUNK; c++) {
    size_t ci = (size_t)c * stride + i;
    float a = Aprod[ci];
    float he = Hc[ci];
    Hc[ci] = hin;
    hin = a * hin + he;
  }
}

// ---------------------------------------------------------------------------
// chunked scan pass 2 with LDS staging; y gathered in LDS, coalesced store.
// y aliases dt (tile reads dt before y writes; (t,e) partitioned by block).
// ---------------------------------------------------------------------------
__global__ __launch_bounds__(256) void k_scan2(const float* __restrict__ dt,
                                               const float* __restrict__ xc,
                                               const float* __restrict__ xz,
                                               const float* __restrict__ dbl,
                                               const float* __restrict__ Alog,
                                               const float* __restrict__ Dp,
                                               const float* __restrict__ Hin,
                                               float* __restrict__ y) {
  __shared__ float sDt[STILE][16], sXc[STILE][16], sZ[STILE][16];
  __shared__ float sB[STILE][16], sC[STILE][16], sY[STILE][16];
  const int tid = threadIdx.x;
  const int n = tid & 15;
  const int es = tid >> 4;
  const int b = blockIdx.x / (DI / 16);
  const int eg = blockIdx.x % (DI / 16);
  const int c = blockIdx.y;
  const int e0 = eg * 16;
  const int e = e0 + es;
  const int tok = tid >> 4, idx = tid & 15;
  const float A = -__expf(Alog[(size_t)e * DSN + n]);
  const float dp = Dp[e];
  size_t ci = (((size_t)c * BB + b) * DI + e) * DSN + n;
  float h = Hin[ci];
  const int l0 = c * LCH;
  const int l1 = (l0 + LCH < LL) ? (l0 + LCH) : LL;
  const size_t tbase = (size_t)b * LL;
  for (int lt = l0; lt < l1; lt += STILE) {
    int cnt = (l1 - lt < STILE) ? (l1 - lt) : STILE;
    if (tok < cnt) {
      size_t t = tbase + lt + tok;
      sDt[tok][idx] = dt[t * DI + e0 + idx];
      sXc[tok][idx] = xc[t * DI + e0 + idx];
      sZ[tok][idx] = xz[t * (2 * DI) + DI + e0 + idx];
      sB[tok][idx] = dbl[t * 56 + DTR + idx];
      sC[tok][idx] = dbl[t * 56 + DTR + DSN + idx];
    }
    __syncthreads();
    for (int j = 0; j < cnt; j++) {
      float dtv = sDt[j][es];
      float xcv = sXc[j][es];
      float dA = __expf(dtv * A);
      h = dA * h + (dtv * xcv) * sB[j][n];
      float contrib = h * sC[j][n];
#pragma unroll
      for (int o = 1; o < 16; o <<= 1) contrib += __shfl_xor(contrib, o);
      if (n == 0) {
        float zv = sZ[j][es];
        float sz = zv * (1.f / (1.f + __expf(-zv)));
        sY[j][es] = (contrib + xcv * dp) * sz;
      }
    }
    __syncthreads();
    if (tok < cnt) {
      y[(tbase + lt + tok) * DI + e0 + idx] = sY[tok][idx];
    }
    __syncthreads();
  }
}

// ---------------------------------------------------------------------------
// final: LN(res[b,0]+hid[b,0]) -> head GEMM
// ---------------------------------------------------------------------------
__global__ __launch_bounds__(256) void k_final(const float* __restrict__ res,
                                               const float* __restrict__ hid,
                                               const float* __restrict__ nfw,
                                               const float* __restrict__ nfb,
                                               const float* __restrict__ hw,
                                               const float* __restrict__ hb,
                                               float* __restrict__ out) {
  const int b = blockIdx.x;
  const int tid = threadIdx.x;
  __shared__ float u0[DD];
  __shared__ float ls[4], lq[4];
  const size_t t0 = (size_t)b * LL * DD;
  float v0, v1 = 0.f;
  float s = 0.f, sq = 0.f;
  v0 = res[t0 + tid] + hid[t0 + tid];
  s += v0; sq += v0 * v0;
  if (tid < 128) {
    v1 = res[t0 + 256 + tid] + hid[t0 + 256 + tid];
    s += v1; sq += v1 * v1;
  }
#pragma unroll
  for (int o = 32; o > 0; o >>= 1) { s += __shfl_xor(s, o); sq += __shfl_xor(sq, o); }
  if ((tid & 63) == 0) { ls[tid >> 6] = s; lq[tid >> 6] = sq; }
  __syncthreads();
  float st = ls[0] + ls[1] + ls[2] + ls[3];
  float qt = lq[0] + lq[1] + lq[2] + lq[3];
  float mu = st * (1.f / 384.f);
  float var = qt * (1.f / 384.f) - mu * mu;
  float rs = rsqrtf(var + EPSV);
  u0[tid] = (v0 - mu) * rs * nfw[tid] + nfb[tid];
  if (tid < 128) u0[256 + tid] = (v1 - mu) * rs * nfw[256 + tid] + nfb[256 + tid];
  __syncthreads();
  for (int c = tid; c < NC; c += 256) {
    float acc = hb[c];
    const float* wrow = hw + (size_t)c * DD;
    for (int d = 0; d < DD; d += 4) {
      float4 w4 = *(const float4*)&wrow[d];
      acc += u0[d] * w4.x + u0[d + 1] * w4.y + u0[d + 2] * w4.z + u0[d + 3] * w4.w;
    }
    out[(size_t)b * NC + c] = acc;
  }
}

// ---------------------------------------------------------------------------
extern "C" void kernel_launch(void* const* d_in, const int* in_sizes, int n_in,
                              void* d_out, int out_size, void* d_ws, size_t ws_size,
                              hipStream_t stream) {
  const float* x       = (const float*)d_in[0];
  const float* patch_w = (const float*)d_in[1];
  const float* patch_b = (const float*)d_in[2];
  const float* cls     = (const float*)d_in[3];
  const float* pos     = (const float*)d_in[4];
  const float* in_proj = (const float*)d_in[5];
  const float* conv_w  = (const float*)d_in[6];
  const float* conv_b  = (const float*)d_in[7];
  const float* x_proj  = (const float*)d_in[8];
  const float* dt_w    = (const float*)d_in[9];
  const float* dt_b    = (const float*)d_in[10];
  const float* A_log   = (const float*)d_in[11];
  const float* D_ssm   = (const float*)d_in[12];
  const float* out_w   = (const float*)d_in[13];
  const float* norm_w  = (const float*)d_in[14];
  const float* norm_b  = (const float*)d_in[15];
  const float* normf_w = (const float*)d_in[16];
  const float* normf_b = (const float*)d_in[17];
  const float* head_w  = (const float*)d_in[18];
  const float* head_b  = (const float*)d_in[19];
  float* out = (float*)d_out;

  float* ws = (float*)d_ws;
  float* res = ws;  ws += (size_t)TT * DD;
  float* hid = ws;  ws += (size_t)TT * DD;
  float* u   = ws;  ws += (size_t)TT * DD;
  float* xzb = ws;  ws += (size_t)TT * 2 * DI;
  float* xcb = ws;  ws += (size_t)TT * DI;
  float* dbl = ws;  ws += (size_t)TT * 56;
  float* dtb = ws;  ws += (size_t)TT * DI;
  float* crg = ws;  ws += (size_t)TT * DI;   // 2*NCHUNK*BB*DI*DSN <= TT*DI
  float* yb  = dtb;                          // y aliases dt (same-block RAW order)
  float* Aprod = crg;
  float* Hc    = crg + (size_t)NCHUNK * BB * DI * DSN;

  k_init<<<(TT * DD + 255) / 256, 256, 0, stream>>>(cls, pos, res, hid);
  k_patch<<<dim3(49, 6), 256, 0, stream>>>(x, patch_w, patch_b, pos, hid);

  for (int layer = 0; layer < DEPTH; layer++) {
    k_addln<<<TT, 128, 0, stream>>>(res, hid, u, norm_w + layer * DD, norm_b + layer * DD);
    // in_proj: u (3152,384) @ Win^T (1536,384) -> xz (3152,1536)  [bf16 MFMA]
    k_gemm_mfma<<<dim3(50, 24), 256, 0, stream>>>(
        u, DD, in_proj + (size_t)layer * 2 * DI * DD, DD, xzb, 2 * DI, TT, 2 * DI, DD);
    k_conv<<<(TT * DI) / 256, 256, 0, stream>>>(xzb, conv_w + layer * DI * 4,
                                                conv_b + layer * DI, xcb);
    // x_proj: xc (3152,768) @ Wx^T (56,768) -> dbl (3152,56)
    k_gemm16<true><<<dim3(197, 1), 256, 0, stream>>>(
        xcb, DI, x_proj + (size_t)layer * 56 * DI, DI, dbl, 56, TT, 56, DI);
    // dt: dbl[:, :24] @ Wdt^T (768,24) + bdt, softplus -> dt (3152,768)
    k_gemm64<1, false, false><<<dim3(50, 12), 256, 0, stream>>>(
        dbl, 56, dt_w + (size_t)layer * DI * DTR, DTR, dtb, DI, TT, DI, DTR,
        dt_b + layer * DI);
    // chunked scan: pass1 -> carry -> pass2
    k_scan1<<<dim3(BB * (DI / 16), NCHUNK), 256, 0, stream>>>(
        dtb, xcb, dbl, A_log + (size_t)layer * DI * DSN, Aprod, Hc);
    k_scan_carry<<<(BB * DI * DSN + 255) / 256, 256, 0, stream>>>(Aprod, Hc);
    k_scan2<<<dim3(BB * (DI / 16), NCHUNK), 256, 0, stream>>>(
        dtb, xcb, xzb, dbl, A_log + (size_t)layer * DI * DSN,
        D_ssm + layer * DI, Hc, yb);
    // out_proj: y (3152,768) @ Wout^T (384,768) -> hid (3152,384)  [bf16 MFMA]
    k_gemm_mfma<<<dim3(50, 6), 256, 0, stream>>>(
        yb, DI, out_w + (size_t)layer * DD * DI, DI, hid, DD, TT, DD, DI);
  }

  k_final<<<BB, 256, 0, stream>>>(res, hid, normf_w, normf_b, head_w, head_b, out);
}

// Round 4
// 4093.264 us; speedup vs baseline: 2.0649x; 1.1310x over previous
//
#include <hip/hip_runtime.h>
#include <hip/hip_bf16.h>
#include <math.h>

// Model dims
#define BB     16
#define LL     197
#define DD     384
#define DEPTH  24
#define DI     768
#define DSN    16
#define DTR    24
#define NC     1000
#define TT     (BB*LL)      // 3152 tokens
#define NPATCH 196
#define EPSV   1e-5f

// chunked scan config
#define NCHUNK 6
#define LCH    33           // ceil(197/6)
#define STILE  16           // tokens staged per LDS tile

typedef __attribute__((ext_vector_type(8))) short short8;
typedef __attribute__((ext_vector_type(4))) float f32x4;

__device__ __forceinline__ short f2bf(float f) {
  union { float f; unsigned u; } v; v.f = f;
  unsigned u = v.u + 0x7fffu + ((v.u >> 16) & 1u);
  return (short)(u >> 16);
}

// ---------------------------------------------------------------------------
// init
// ---------------------------------------------------------------------------
__global__ __launch_bounds__(256) void k_init(const float* __restrict__ cls,
                                              const float* __restrict__ pos,
                                              float* __restrict__ res,
                                              float* __restrict__ hid) {
  int i = blockIdx.x * 256 + threadIdx.x;
  if (i < TT * DD) res[i] = 0.f;
  if (i < BB * DD) {
    int b = i / DD, d = i % DD;
    hid[(size_t)(b * LL) * DD + d] = cls[d] + pos[d];
  }
}

// ---------------------------------------------------------------------------
// patch embed: bf16 MFMA GEMM with fused im2col.
// M=3136 (49x64 exact), N=384 (6x64 exact), K=768.
// ---------------------------------------------------------------------------
__global__ __launch_bounds__(256) void k_patch(const float* __restrict__ x,
                                               const float* __restrict__ pw,
                                               const float* __restrict__ pb,
                                               const float* __restrict__ pos,
                                               float* __restrict__ hid) {
  __shared__ short sA[64 * 40];
  __shared__ short sB[64 * 40];
  const int tid = threadIdx.x;
  const int m0 = blockIdx.x * 64, n0 = blockIdx.y * 64;
  const int srow = tid >> 2;
  const int skq = (tid & 3) * 8;
  const int lane = tid & 63, w = tid >> 6;
  const int wm = (w >> 1) * 32, wn = (w & 1) * 32;
  const int fr = lane & 15;
  const int fk = (lane >> 4) * 8;
  f32x4 acc[2][2] = {};
  const int m = m0 + srow;
  const int b = m / NPATCH;
  const int p = m % NPATCH;
  const int ph = p / 14, pwi = p % 14;
  const float* Wrow = pw + (size_t)(n0 + srow) * 768 + skq;
  for (int k0 = 0; k0 < 768; k0 += 32) {
    int k = k0 + skq;                       // 8-aligned: stays within one rr row
    int c = k >> 8, rr = (k >> 4) & 15, kw = k & 15;
    const float* xrow = &x[(size_t)(((b * 3 + c) * 224) + (ph * 16 + rr)) * 224 +
                           (pwi * 16 + kw)];
    float4 a0 = *(const float4*)&xrow[0];
    float4 a1 = *(const float4*)&xrow[4];
    float4 b0 = *(const float4*)&Wrow[k0];
    float4 b1 = *(const float4*)&Wrow[k0 + 4];
    short8 av = {f2bf(a0.x), f2bf(a0.y), f2bf(a0.z), f2bf(a0.w),
                 f2bf(a1.x), f2bf(a1.y), f2bf(a1.z), f2bf(a1.w)};
    short8 bv = {f2bf(b0.x), f2bf(b0.y), f2bf(b0.z), f2bf(b0.w),
                 f2bf(b1.x), f2bf(b1.y), f2bf(b1.z), f2bf(b1.w)};
    *(short8*)&sA[srow * 40 + skq] = av;
    *(short8*)&sB[srow * 40 + skq] = bv;
    __syncthreads();
    short8 af0 = *(const short8*)&sA[(wm + fr) * 40 + fk];
    short8 af1 = *(const short8*)&sA[(wm + 16 + fr) * 40 + fk];
    short8 bf0 = *(const short8*)&sB[(wn + fr) * 40 + fk];
    short8 bf1 = *(const short8*)&sB[(wn + 16 + fr) * 40 + fk];
    acc[0][0] = __builtin_amdgcn_mfma_f32_16x16x32_bf16(af0, bf0, acc[0][0], 0, 0, 0);
    acc[0][1] = __builtin_amdgcn_mfma_f32_16x16x32_bf16(af0, bf1, acc[0][1], 0, 0, 0);
    acc[1][0] = __builtin_amdgcn_mfma_f32_16x16x32_bf16(af1, bf0, acc[1][0], 0, 0, 0);
    acc[1][1] = __builtin_amdgcn_mfma_f32_16x16x32_bf16(af1, bf1, acc[1][1], 0, 0, 0);
    __syncthreads();
  }
#pragma unroll
  for (int i = 0; i < 2; i++)
#pragma unroll
    for (int j = 0; j < 2; j++)
#pragma unroll
      for (int q = 0; q < 4; q++) {
        int mm = m0 + wm + i * 16 + (lane >> 4) * 4 + q;
        int nn = n0 + wn + j * 16 + (lane & 15);
        int b2 = mm / NPATCH, pp = mm % NPATCH;
        int tok = b2 * LL + 1 + pp;
        hid[(size_t)tok * DD + nn] = acc[i][j][q] + pb[nn] + pos[(size_t)(1 + pp) * DD + nn];
      }
}

// ---------------------------------------------------------------------------
// bf16 MFMA GEMM: C[M,N] = A[M,K] * W[N,K]^T, fp32 in/out, bf16 compute.
// 64x64 tile, 4 waves each 32x32 (2x2 of 16x16x32). K%32==0, N%64==0.
// ---------------------------------------------------------------------------
__global__ __launch_bounds__(256) void k_gemm_mfma(const float* __restrict__ A, int lda,
                                                   const float* __restrict__ W, int ldb,
                                                   float* __restrict__ C, int ldc,
                                                   int M, int N, int K) {
  __shared__ short sA[64 * 40];
  __shared__ short sB[64 * 40];
  const int tid = threadIdx.x;
  const int m0 = blockIdx.x * 64, n0 = blockIdx.y * 64;
  const int srow = tid >> 2;
  const int skq = (tid & 3) * 8;
  const int lane = tid & 63, w = tid >> 6;
  const int wm = (w >> 1) * 32, wn = (w & 1) * 32;
  const int fr = lane & 15;
  const int fk = (lane >> 4) * 8;
  f32x4 acc[2][2] = {};
  const int am = m0 + srow;
  const bool aok = am < M;
  const float* Arow = A + (size_t)am * lda + skq;
  const float* Wrow = W + (size_t)(n0 + srow) * ldb + skq;
  for (int k0 = 0; k0 < K; k0 += 32) {
    float4 a0 = {0, 0, 0, 0}, a1 = {0, 0, 0, 0};
    if (aok) {
      a0 = *(const float4*)&Arow[k0];
      a1 = *(const float4*)&Arow[k0 + 4];
    }
    float4 b0 = *(const float4*)&Wrow[k0];
    float4 b1 = *(const float4*)&Wrow[k0 + 4];
    short8 av = {f2bf(a0.x), f2bf(a0.y), f2bf(a0.z), f2bf(a0.w),
                 f2bf(a1.x), f2bf(a1.y), f2bf(a1.z), f2bf(a1.w)};
    short8 bv = {f2bf(b0.x), f2bf(b0.y), f2bf(b0.z), f2bf(b0.w),
                 f2bf(b1.x), f2bf(b1.y), f2bf(b1.z), f2bf(b1.w)};
    *(short8*)&sA[srow * 40 + skq] = av;
    *(short8*)&sB[srow * 40 + skq] = bv;
    __syncthreads();
    short8 af0 = *(const short8*)&sA[(wm + fr) * 40 + fk];
    short8 af1 = *(const short8*)&sA[(wm + 16 + fr) * 40 + fk];
    short8 bf0 = *(const short8*)&sB[(wn + fr) * 40 + fk];
    short8 bf1 = *(const short8*)&sB[(wn + 16 + fr) * 40 + fk];
    acc[0][0] = __builtin_amdgcn_mfma_f32_16x16x32_bf16(af0, bf0, acc[0][0], 0, 0, 0);
    acc[0][1] = __builtin_amdgcn_mfma_f32_16x16x32_bf16(af0, bf1, acc[0][1], 0, 0, 0);
    acc[1][0] = __builtin_amdgcn_mfma_f32_16x16x32_bf16(af1, bf0, acc[1][0], 0, 0, 0);
    acc[1][1] = __builtin_amdgcn_mfma_f32_16x16x32_bf16(af1, bf1, acc[1][1], 0, 0, 0);
    __syncthreads();
  }
#pragma unroll
  for (int i = 0; i < 2; i++)
#pragma unroll
    for (int j = 0; j < 2; j++)
#pragma unroll
      for (int q = 0; q < 4; q++) {
        int mm = m0 + wm + i * 16 + (lane >> 4) * 4 + q;
        int nn = n0 + wn + j * 16 + (lane & 15);
        if (mm < M) C[(size_t)mm * ldc + nn] = acc[i][j][q];
      }
}

// ---------------------------------------------------------------------------
// dt projection: bf16 MFMA, M=3152, N=768, K=24 zero-padded to 32 (1 k-iter).
// C = softplus(dbl[:, :24] @ Wdt^T + bias), fp32 out (ldc=768).
// ---------------------------------------------------------------------------
__global__ __launch_bounds__(256) void k_dtproj(const float* __restrict__ A,   // dbl, lda=56
                                                const float* __restrict__ W,   // Wdt (768,24)
                                                const float* __restrict__ bias,
                                                float* __restrict__ C) {
  __shared__ short sA[64 * 40];
  __shared__ short sB[64 * 40];
  const int tid = threadIdx.x;
  const int m0 = blockIdx.x * 64, n0 = blockIdx.y * 64;
  const int srow = tid >> 2;
  const int skq = (tid & 3) * 8;     // 0,8,16,24
  const int lane = tid & 63, w = tid >> 6;
  const int wm = (w >> 1) * 32, wn = (w & 1) * 32;
  const int fr = lane & 15;
  const int fk = (lane >> 4) * 8;
  f32x4 acc[2][2] = {};
  const int am = m0 + srow;
  short8 av = {0, 0, 0, 0, 0, 0, 0, 0}, bv = {0, 0, 0, 0, 0, 0, 0, 0};
  if (skq < 24) {
    if (am < TT) {
      float4 a0 = *(const float4*)&A[(size_t)am * 56 + skq];
      float4 a1 = *(const float4*)&A[(size_t)am * 56 + skq + 4];
      av = short8{f2bf(a0.x), f2bf(a0.y), f2bf(a0.z), f2bf(a0.w),
                  f2bf(a1.x), f2bf(a1.y), f2bf(a1.z), f2bf(a1.w)};
    }
    float4 b0 = *(const float4*)&W[(size_t)(n0 + srow) * 24 + skq];
    float4 b1 = *(const float4*)&W[(size_t)(n0 + srow) * 24 + skq + 4];
    bv = short8{f2bf(b0.x), f2bf(b0.y), f2bf(b0.z), f2bf(b0.w),
                f2bf(b1.x), f2bf(b1.y), f2bf(b1.z), f2bf(b1.w)};
  }
  *(short8*)&sA[srow * 40 + skq] = av;
  *(short8*)&sB[srow * 40 + skq] = bv;
  __syncthreads();
  short8 af0 = *(const short8*)&sA[(wm + fr) * 40 + fk];
  short8 af1 = *(const short8*)&sA[(wm + 16 + fr) * 40 + fk];
  short8 bf0 = *(const short8*)&sB[(wn + fr) * 40 + fk];
  short8 bf1 = *(const short8*)&sB[(wn + 16 + fr) * 40 + fk];
  acc[0][0] = __builtin_amdgcn_mfma_f32_16x16x32_bf16(af0, bf0, acc[0][0], 0, 0, 0);
  acc[0][1] = __builtin_amdgcn_mfma_f32_16x16x32_bf16(af0, bf1, acc[0][1], 0, 0, 0);
  acc[1][0] = __builtin_amdgcn_mfma_f32_16x16x32_bf16(af1, bf0, acc[1][0], 0, 0, 0);
  acc[1][1] = __builtin_amdgcn_mfma_f32_16x16x32_bf16(af1, bf1, acc[1][1], 0, 0, 0);
#pragma unroll
  for (int i = 0; i < 2; i++)
#pragma unroll
    for (int j = 0; j < 2; j++)
#pragma unroll
      for (int q = 0; q < 4; q++) {
        int mm = m0 + wm + i * 16 + (lane >> 4) * 4 + q;
        int nn = n0 + wn + j * 16 + (lane & 15);
        if (mm < TT) {
          float v = acc[i][j][q] + bias[nn];
          v = (v > 20.f) ? v : log1pf(__expf(v));
          C[(size_t)mm * DI + nn] = v;
        }
      }
}

// ---------------------------------------------------------------------------
// x_proj: bf16 MFMA, BM=16 (3152=197x16 exact), BN=64 (N=56 padded), K=768.
// Each of 4 waves owns a 16-wide N-quarter; 1 MFMA per k-iter per wave.
// ---------------------------------------------------------------------------
__global__ __launch_bounds__(256) void k_xproj(const float* __restrict__ A,   // xc, lda=768
                                               const float* __restrict__ W,   // (56,768)
                                               float* __restrict__ C) {       // dbl, ldc=56
  __shared__ short sA[16 * 40];
  __shared__ short sB[64 * 40];
  const int tid = threadIdx.x;
  const int m0 = blockIdx.x * 16;
  const int lane = tid & 63, w = tid >> 6;
  const int wn = w * 16;
  const int fr = lane & 15;
  const int fk = (lane >> 4) * 8;
  const int srow = tid >> 2;
  const int skq = (tid & 3) * 8;
  f32x4 acc = {};
  for (int k0 = 0; k0 < DI; k0 += 32) {
    if (tid < 64) {
      float4 a0 = *(const float4*)&A[(size_t)(m0 + srow) * DI + k0 + skq];
      float4 a1 = *(const float4*)&A[(size_t)(m0 + srow) * DI + k0 + skq + 4];
      short8 av = {f2bf(a0.x), f2bf(a0.y), f2bf(a0.z), f2bf(a0.w),
                   f2bf(a1.x), f2bf(a1.y), f2bf(a1.z), f2bf(a1.w)};
      *(short8*)&sA[srow * 40 + skq] = av;
    }
    short8 bv = {0, 0, 0, 0, 0, 0, 0, 0};
    if (srow < 56) {
      float4 b0 = *(const float4*)&W[(size_t)srow * DI + k0 + skq];
      float4 b1 = *(const float4*)&W[(size_t)srow * DI + k0 + skq + 4];
      bv = short8{f2bf(b0.x), f2bf(b0.y), f2bf(b0.z), f2bf(b0.w),
                  f2bf(b1.x), f2bf(b1.y), f2bf(b1.z), f2bf(b1.w)};
    }
    *(short8*)&sB[srow * 40 + skq] = bv;
    __syncthreads();
    short8 af = *(const short8*)&sA[fr * 40 + fk];
    short8 bf = *(const short8*)&sB[(wn + fr) * 40 + fk];
    acc = __builtin_amdgcn_mfma_f32_16x16x32_bf16(af, bf, acc, 0, 0, 0);
    __syncthreads();
  }
#pragma unroll
  for (int q = 0; q < 4; q++) {
    int mm = m0 + (lane >> 4) * 4 + q;
    int nn = wn + (lane & 15);
    if (nn < 56) C[(size_t)mm * 56 + nn] = acc[q];
  }
}

// ---------------------------------------------------------------------------
// res += hid; u = LN(res) * nw + nb
// ---------------------------------------------------------------------------
__global__ __launch_bounds__(128) void k_addln(float* __restrict__ res,
                                               const float* __restrict__ hid,
                                               float* __restrict__ u,
                                               const float* __restrict__ nw,
                                               const float* __restrict__ nb) {
  const int t = blockIdx.x;
  const int tid = threadIdx.x;
  float r[3];
  float s = 0.f, sq = 0.f;
#pragma unroll
  for (int j = 0; j < 3; j++) {
    int d = tid + j * 128;
    float v = res[(size_t)t * DD + d] + hid[(size_t)t * DD + d];
    res[(size_t)t * DD + d] = v;
    r[j] = v;
    s += v; sq += v * v;
  }
#pragma unroll
  for (int o = 32; o > 0; o >>= 1) { s += __shfl_xor(s, o); sq += __shfl_xor(sq, o); }
  __shared__ float ls[2], lq[2];
  int w = tid >> 6;
  if ((tid & 63) == 0) { ls[w] = s; lq[w] = sq; }
  __syncthreads();
  float st = ls[0] + ls[1], qt = lq[0] + lq[1];
  float mu = st * (1.f / 384.f);
  float var = qt * (1.f / 384.f) - mu * mu;
  float rs = rsqrtf(var + EPSV);
#pragma unroll
  for (int j = 0; j < 3; j++) {
    int d = tid + j * 128;
    u[(size_t)t * DD + d] = (r[j] - mu) * rs * nw[d] + nb[d];
  }
}

// ---------------------------------------------------------------------------
// causal depthwise conv (k=4, left pad 3) + bias + SiLU
// ---------------------------------------------------------------------------
__global__ __launch_bounds__(256) void k_conv(const float* __restrict__ xz,
                                              const float* __restrict__ wc,
                                              const float* __restrict__ bc,
                                              float* __restrict__ xc) {
  int i = blockIdx.x * 256 + threadIdx.x;
  if (i >= TT * DI) return;
  int e = i % DI;
  int t = i / DI;
  int b = t / LL, l = t % LL;
  float4 w = *(const float4*)&wc[e * 4];
  float acc = bc[e];
  const float* base = xz + (size_t)(b * LL) * (2 * DI) + e;
  if (l >= 3) acc += base[(size_t)(l - 3) * (2 * DI)] * w.x;
  if (l >= 2) acc += base[(size_t)(l - 2) * (2 * DI)] * w.y;
  if (l >= 1) acc += base[(size_t)(l - 1) * (2 * DI)] * w.z;
  acc += base[(size_t)l * (2 * DI)] * w.w;
  xc[i] = acc * (1.f / (1.f + __expf(-acc)));
}

// ---------------------------------------------------------------------------
// chunked scan pass 1 with LDS token staging
// ---------------------------------------------------------------------------
__global__ __launch_bounds__(256) void k_scan1(const float* __restrict__ dt,
                                               const float* __restrict__ xc,
                                               const float* __restrict__ dbl,
                                               const float* __restrict__ Alog,
                                               float* __restrict__ Aprod,
                                               float* __restrict__ Hend) {
  __shared__ float sDt[STILE][16], sXc[STILE][16], sB[STILE][16];
  const int tid = threadIdx.x;
  const int n = tid & 15;
  const int es = tid >> 4;
  const int b = blockIdx.x / (DI / 16);
  const int eg = blockIdx.x % (DI / 16);
  const int c = blockIdx.y;
  const int e0 = eg * 16;
  const int e = e0 + es;
  const int tok = tid >> 4, idx = tid & 15;
  const float A = -__expf(Alog[(size_t)e * DSN + n]);
  float h = 0.f, ap = 1.f;
  const int l0 = c * LCH;
  const int l1 = (l0 + LCH < LL) ? (l0 + LCH) : LL;
  const size_t tbase = (size_t)b * LL;
  for (int lt = l0; lt < l1; lt += STILE) {
    int cnt = (l1 - lt < STILE) ? (l1 - lt) : STILE;
    if (tok < cnt) {
      size_t t = tbase + lt + tok;
      sDt[tok][idx] = dt[t * DI + e0 + idx];
      sXc[tok][idx] = xc[t * DI + e0 + idx];
      sB[tok][idx] = dbl[t * 56 + DTR + idx];
    }
    __syncthreads();
    for (int j = 0; j < cnt; j++) {
      float dtv = sDt[j][es];
      float dA = __expf(dtv * A);
      h = dA * h + (dtv * sXc[j][es]) * sB[j][n];
      ap *= dA;
    }
    __syncthreads();
  }
  size_t ci = (((size_t)c * BB + b) * DI + e) * DSN + n;
  Aprod[ci] = ap;
  Hend[ci] = h;
}

// ---------------------------------------------------------------------------
// carry combine
// ---------------------------------------------------------------------------
__global__ __launch_bounds__(256) void k_scan_carry(const float* __restrict__ Aprod,
                                                    float* __restrict__ Hc) {
  int i = blockIdx.x * 256 + threadIdx.x;
  if (i >= BB * DI * DSN) return;
  const size_t stride = (size_t)BB * DI * DSN;
  float hin = 0.f;
#pragma unroll
  for (int c = 0; c < NCHUNK; c++) {
    size_t ci = (size_t)c * stride + i;
    float a = Aprod[ci];
    float he = Hc[ci];
    Hc[ci] = hin;
    hin = a * hin + he;
  }
}

// ---------------------------------------------------------------------------
// chunked scan pass 2 with LDS staging; y aliases dt (same-block RAW order).
// ---------------------------------------------------------------------------
__global__ __launch_bounds__(256) void k_scan2(const float* __restrict__ dt,
                                               const float* __restrict__ xc,
                                               const float* __restrict__ xz,
                                               const float* __restrict__ dbl,
                                               const float* __restrict__ Alog,
                                               const float* __restrict__ Dp,
                                               const float* __restrict__ Hin,
                                               float* __restrict__ y) {
  __shared__ float sDt[STILE][16], sXc[STILE][16], sZ[STILE][16];
  __shared__ float sB[STILE][16], sC[STILE][16], sY[STILE][16];
  const int tid = threadIdx.x;
  const int n = tid & 15;
  const int es = tid >> 4;
  const int b = blockIdx.x / (DI / 16);
  const int eg = blockIdx.x % (DI / 16);
  const int c = blockIdx.y;
  const int e0 = eg * 16;
  const int e = e0 + es;
  const int tok = tid >> 4, idx = tid & 15;
  const float A = -__expf(Alog[(size_t)e * DSN + n]);
  const float dp = Dp[e];
  size_t ci = (((size_t)c * BB + b) * DI + e) * DSN + n;
  float h = Hin[ci];
  const int l0 = c * LCH;
  const int l1 = (l0 + LCH < LL) ? (l0 + LCH) : LL;
  const size_t tbase = (size_t)b * LL;
  for (int lt = l0; lt < l1; lt += STILE) {
    int cnt = (l1 - lt < STILE) ? (l1 - lt) : STILE;
    if (tok < cnt) {
      size_t t = tbase + lt + tok;
      sDt[tok][idx] = dt[t * DI + e0 + idx];
      sXc[tok][idx] = xc[t * DI + e0 + idx];
      sZ[tok][idx] = xz[t * (2 * DI) + DI + e0 + idx];
      sB[tok][idx] = dbl[t * 56 + DTR + idx];
      sC[tok][idx] = dbl[t * 56 + DTR + DSN + idx];
    }
    __syncthreads();
    for (int j = 0; j < cnt; j++) {
      float dtv = sDt[j][es];
      float xcv = sXc[j][es];
      float dA = __expf(dtv * A);
      h = dA * h + (dtv * xcv) * sB[j][n];
      float contrib = h * sC[j][n];
#pragma unroll
      for (int o = 1; o < 16; o <<= 1) contrib += __shfl_xor(contrib, o);
      if (n == 0) {
        float zv = sZ[j][es];
        float sz = zv * (1.f / (1.f + __expf(-zv)));
        sY[j][es] = (contrib + xcv * dp) * sz;
      }
    }
    __syncthreads();
    if (tok < cnt) {
      y[(tbase + lt + tok) * DI + e0 + idx] = sY[tok][idx];
    }
    __syncthreads();
  }
}

// ---------------------------------------------------------------------------
// final: LN(res[b,0]+hid[b,0]) -> head GEMM
// ---------------------------------------------------------------------------
__global__ __launch_bounds__(256) void k_final(const float* __restrict__ res,
                                               const float* __restrict__ hid,
                                               const float* __restrict__ nfw,
                                               const float* __restrict__ nfb,
                                               const float* __restrict__ hw,
                                               const float* __restrict__ hb,
                                               float* __restrict__ out) {
  const int b = blockIdx.x;
  const int tid = threadIdx.x;
  __shared__ float u0[DD];
  __shared__ float ls[4], lq[4];
  const size_t t0 = (size_t)b * LL * DD;
  float v0, v1 = 0.f;
  float s = 0.f, sq = 0.f;
  v0 = res[t0 + tid] + hid[t0 + tid];
  s += v0; sq += v0 * v0;
  if (tid < 128) {
    v1 = res[t0 + 256 + tid] + hid[t0 + 256 + tid];
    s += v1; sq += v1 * v1;
  }
#pragma unroll
  for (int o = 32; o > 0; o >>= 1) { s += __shfl_xor(s, o); sq += __shfl_xor(sq, o); }
  if ((tid & 63) == 0) { ls[tid >> 6] = s; lq[tid >> 6] = sq; }
  __syncthreads();
  float st = ls[0] + ls[1] + ls[2] + ls[3];
  float qt = lq[0] + lq[1] + lq[2] + lq[3];
  float mu = st * (1.f / 384.f);
  float var = qt * (1.f / 384.f) - mu * mu;
  float rs = rsqrtf(var + EPSV);
  u0[tid] = (v0 - mu) * rs * nfw[tid] + nfb[tid];
  if (tid < 128) u0[256 + tid] = (v1 - mu) * rs * nfw[256 + tid] + nfb[256 + tid];
  __syncthreads();
  for (int c = tid; c < NC; c += 256) {
    float acc = hb[c];
    const float* wrow = hw + (size_t)c * DD;
    for (int d = 0; d < DD; d += 4) {
      float4 w4 = *(const float4*)&wrow[d];
      acc += u0[d] * w4.x + u0[d + 1] * w4.y + u0[d + 2] * w4.z + u0[d + 3] * w4.w;
    }
    out[(size_t)b * NC + c] = acc;
  }
}

// ---------------------------------------------------------------------------
extern "C" void kernel_launch(void* const* d_in, const int* in_sizes, int n_in,
                              void* d_out, int out_size, void* d_ws, size_t ws_size,
                              hipStream_t stream) {
  const float* x       = (const float*)d_in[0];
  const float* patch_w = (const float*)d_in[1];
  const float* patch_b = (const float*)d_in[2];
  const float* cls     = (const float*)d_in[3];
  const float* pos     = (const float*)d_in[4];
  const float* in_proj = (const float*)d_in[5];
  const float* conv_w  = (const float*)d_in[6];
  const float* conv_b  = (const float*)d_in[7];
  const float* x_proj  = (const float*)d_in[8];
  const float* dt_w    = (const float*)d_in[9];
  const float* dt_b    = (const float*)d_in[10];
  const float* A_log   = (const float*)d_in[11];
  const float* D_ssm   = (const float*)d_in[12];
  const float* out_w   = (const float*)d_in[13];
  const float* norm_w  = (const float*)d_in[14];
  const float* norm_b  = (const float*)d_in[15];
  const float* normf_w = (const float*)d_in[16];
  const float* normf_b = (const float*)d_in[17];
  const float* head_w  = (const float*)d_in[18];
  const float* head_b  = (const float*)d_in[19];
  float* out = (float*)d_out;

  float* ws = (float*)d_ws;
  float* res = ws;  ws += (size_t)TT * DD;
  float* hid = ws;  ws += (size_t)TT * DD;
  float* u   = ws;  ws += (size_t)TT * DD;
  float* xzb = ws;  ws += (size_t)TT * 2 * DI;
  float* xcb = ws;  ws += (size_t)TT * DI;
  float* dbl = ws;  ws += (size_t)TT * 56;
  float* dtb = ws;  ws += (size_t)TT * DI;
  float* crg = ws;  ws += (size_t)TT * DI;   // 2*NCHUNK*BB*DI*DSN <= TT*DI
  float* yb  = dtb;                          // y aliases dt (same-block RAW order)
  float* Aprod = crg;
  float* Hc    = crg + (size_t)NCHUNK * BB * DI * DSN;

  k_init<<<(TT * DD + 255) / 256, 256, 0, stream>>>(cls, pos, res, hid);
  k_patch<<<dim3(49, 6), 256, 0, stream>>>(x, patch_w, patch_b, pos, hid);

  for (int layer = 0; layer < DEPTH; layer++) {
    k_addln<<<TT, 128, 0, stream>>>(res, hid, u, norm_w + layer * DD, norm_b + layer * DD);
    // in_proj: u (3152,384) @ Win^T (1536,384) -> xz (3152,1536)  [bf16 MFMA]
    k_gemm_mfma<<<dim3(50, 24), 256, 0, stream>>>(
        u, DD, in_proj + (size_t)layer * 2 * DI * DD, DD, xzb, 2 * DI, TT, 2 * DI, DD);
    k_conv<<<(TT * DI) / 256, 256, 0, stream>>>(xzb, conv_w + layer * DI * 4,
                                                conv_b + layer * DI, xcb);
    // x_proj: xc (3152,768) @ Wx^T (56,768) -> dbl (3152,56)  [bf16 MFMA]
    k_xproj<<<dim3(TT / 16), 256, 0, stream>>>(
        xcb, x_proj + (size_t)layer * 56 * DI, dbl);
    // dt: softplus(dbl[:, :24] @ Wdt^T + bdt) -> dt (3152,768)  [bf16 MFMA]
    k_dtproj<<<dim3(50, 12), 256, 0, stream>>>(
        dbl, dt_w + (size_t)layer * DI * DTR, dt_b + layer * DI, dtb);
    // chunked scan: pass1 -> carry -> pass2
    k_scan1<<<dim3(BB * (DI / 16), NCHUNK), 256, 0, stream>>>(
        dtb, xcb, dbl, A_log + (size_t)layer * DI * DSN, Aprod, Hc);
    k_scan_carry<<<(BB * DI * DSN + 255) / 256, 256, 0, stream>>>(Aprod, Hc);
    k_scan2<<<dim3(BB * (DI / 16), NCHUNK), 256, 0, stream>>>(
        dtb, xcb, xzb, dbl, A_log + (size_t)layer * DI * DSN,
        D_ssm + layer * DI, Hc, yb);
    // out_proj: y (3152,768) @ Wout^T (384,768) -> hid (3152,384)  [bf16 MFMA]
    k_gemm_mfma<<<dim3(50, 6), 256, 0, stream>>>(
        yb, DI, out_w + (size_t)layer * DD * DI, DI, hid, DD, TT, DD, DI);
  }

  k_final<<<BB, 256, 0, stream>>>(res, hid, normf_w, normf_b, head_w, head_b, out);
}